// Round 7
// baseline (383.748 us; speedup 1.0000x reference)
//
#include <hip/hip_runtime.h>
#include <cstdint>
#include <cstddef>

#define B_ 2048
#define S_ 168
#define NT_ 5376   // (B_*S_)/64 row-tiles

// ---------- helpers ----------
typedef _Float16 h2_t __attribute__((ext_vector_type(2)));
typedef _Float16 f16x8 __attribute__((ext_vector_type(8)));
typedef float f32x4 __attribute__((ext_vector_type(4)));
typedef unsigned int u32;

__device__ __forceinline__ float dot2h(unsigned a, unsigned b, float c){
    return __builtin_amdgcn_fdot2(__builtin_bit_cast(h2_t, a),
                                  __builtin_bit_cast(h2_t, b), c, false);
}
__device__ __forceinline__ unsigned pack_h2f(float a, float b){
    h2_t v; v.x = (_Float16)a; v.y = (_Float16)b;
    return __builtin_bit_cast(unsigned, v);
}
__device__ __forceinline__ float fast_exp(float x){
    return __builtin_amdgcn_exp2f(x * 1.44269504088896340736f);
}
__device__ __forceinline__ float fast_sigmoid(float x){
    return __builtin_amdgcn_rcpf(1.0f + fast_exp(-x));
}
__device__ __forceinline__ float fast_tanh(float x){
    return 1.0f - 2.0f * __builtin_amdgcn_rcpf(1.0f + fast_exp(2.0f * x));
}
__device__ __forceinline__ void wsync(){
    asm volatile("s_waitcnt lgkmcnt(0)" ::: "memory");
    __builtin_amdgcn_wave_barrier();
}
__device__ __forceinline__ f32x4 mfma16(uint4 a, uint4 b, f32x4 c){
    return __builtin_amdgcn_mfma_f32_16x16x32_f16(
        __builtin_bit_cast(f16x8, a), __builtin_bit_cast(f16x8, b), c, 0, 0, 0);
}
__device__ __forceinline__ uint4 load_bfrag(const float* __restrict__ W, int ldk,
                                            int o, int kk0, int kmax){
    float w[8];
    #pragma unroll
    for (int e = 0; e < 8; ++e){
        int kk = kk0 + e;
        w[e] = (kk < kmax) ? W[o*ldk + kk] : 0.f;
    }
    uint4 r;
    r.x = pack_h2f(w[0], w[1]); r.y = pack_h2f(w[2], w[3]);
    r.z = pack_h2f(w[4], w[5]); r.w = pack_h2f(w[6], w[7]);
    return r;
}

// ---------- kernel 1: attention over stations (proven) ----------
__global__ void nbst_attn(const float* __restrict__ sn, const float* __restrict__ Wn,
                          const float* __restrict__ bn, const float* __restrict__ Wa,
                          float* __restrict__ attnO){
    __shared__ float WnL[64*16];
    __shared__ float WsL[64];
    __shared__ float bnL[64];
    const int tid = threadIdx.x;
    for (int e = tid; e < 1024; e += 256) WnL[e] = Wn[e];
    if (tid < 64){ WsL[tid] = Wa[64 + tid]; bnL[tid] = bn[tid]; }
    __syncthreads();
    const int wv = tid >> 6, l = tid & 63;
    const int b = blockIdx.x * 4 + wv;
    const float* xp = sn + ((size_t)b * 64 + l) * 16;
    float x[16];
    #pragma unroll
    for (int k = 0; k < 16; ++k) x[k] = xp[k];
    float e_i = 0.f;
    for (int h = 0; h < 64; ++h){
        float acc = bnL[h];
        #pragma unroll
        for (int k = 0; k < 16; ++k) acc += x[k] * WnL[h*16 + k];
        e_i += fast_tanh(acc) * WsL[h];
    }
    float m = e_i;
    #pragma unroll
    for (int s = 32; s >= 1; s >>= 1) m = fmaxf(m, __shfl_xor(m, s));
    float p = fast_exp(e_i - m);
    float ssum = p;
    #pragma unroll
    for (int s = 32; s >= 1; s >>= 1) ssum += __shfl_xor(ssum, s);
    attnO[(size_t)b*64 + l] = p * __builtin_amdgcn_rcpf(ssum);
}

// ---------- kernel 2: persistent MLP + xg0 GEMM (proven) ----------
#define A0_CAT 0      // [64][36] u32: 0..17 cat pairs, 18..35 zero (K pad)
#define A0_H1  2304   // [64][20]
#define A0_FT  3584   // [64][68]
#define A0_WM  7936   // [8 frags][64 lanes][4]
#define A0_EMB 9984   // 260 f32
#define A0_ATT 10244  // 128 f32: attn rows b0, b0+1
#define A0_TOT 10372

__global__ __launch_bounds__(256, 2)
void nbst_mlpxg0(const float* __restrict__ sf, const int* __restrict__ se,
                 const float* __restrict__ e0, const float* __restrict__ e1,
                 const float* __restrict__ e2, const float* __restrict__ e3,
                 const float* __restrict__ e4,
                 const float* __restrict__ Wd1, const float* __restrict__ bd1,
                 const float* __restrict__ Wd2, const float* __restrict__ bd2,
                 const float* __restrict__ Wih0, const float* __restrict__ attnI,
                 _Float16* __restrict__ xgout)
{
    __shared__ u32 sm[A0_TOT];
    float* smF = reinterpret_cast<float*>(sm);
    const int tid = threadIdx.x;
    const int w = tid >> 6, l = tid & 63;

    // ---- one-time prologue ----
    for (int e = tid; e < 260; e += 256){
        float v;
        if (e < 48)       v = e0[e];
        else if (e < 88)  v = e1[e-48];
        else if (e < 136) v = e2[e-88];
        else if (e < 164) v = e3[e-136];
        else              v = e4[e-164];
        smF[A0_EMB + e] = v;
    }
    for (int f = w; f < 8; f += 4){
        uint4 fr;
        if (f < 4){ int n = f >> 1, ks = f & 1;
                    fr = load_bfrag(Wd1, 36, 16*n + (l&15), 32*ks + 8*(l>>4), 36); }
        else      { int n = f - 4;
                    fr = load_bfrag(Wd2, 32, 16*n + (l&15), 8*(l>>4), 32); }
        *reinterpret_cast<uint4*>(sm + A0_WM + (f*64 + l)*4) = fr;
    }
    uint4 bw[3][4];
    #pragma unroll
    for (int nn = 0; nn < 3; ++nn)
        #pragma unroll
        for (int ks = 0; ks < 4; ++ks)
            bw[nn][ks] = load_bfrag(Wih0, 128, 16*(w + 4*nn) + (l&15), 32*ks + 8*(l>>4), 128);
    for (int e = tid; e < 64*18; e += 256){           // zero CAT K-pad once
        int row = e / 18, j = 18 + e % 18;
        sm[A0_CAT + row*36 + j] = 0u;
    }
    const float bb10 = bd1[(l&15)],  bb11 = bd1[16+(l&15)];
    const float bb20 = bd2[(l&15)],  bb21 = bd2[16+(l&15)];
    const float bb22 = bd2[32+(l&15)], bb23 = bd2[48+(l&15)];
    __syncthreads();

    // ---- persistent tile loop ----
    for (int tile = blockIdx.x; tile < NT_; tile += gridDim.x){
        const int R0 = tile * 64;
        const int b0 = R0 / S_;
        const int eB = (b0 + 1) * S_;
        if (tid < 128){
            int bi = b0 + (tid >> 6); if (bi >= B_) bi = B_ - 1;
            smF[A0_ATT + tid] = attnI[(size_t)bi*64 + (tid & 63)];
        }
        for (int e = tid; e < 64*18; e += 256){
            int row = e / 18, j = e % 18;
            int R = R0 + row;
            float c0, c1;
            if (j < 8){
                c0 = sf[(size_t)R*16 + 2*j]; c1 = sf[(size_t)R*16 + 2*j + 1];
            } else {
                int jj = j - 8, ebl = jj >> 1, d0 = (jj & 1) * 2;
                int idx = se[(size_t)R*5 + ebl] - (ebl >= 2 ? 1 : 0);
                const int toff = (ebl==0)?0:(ebl==1)?48:(ebl==2)?88:(ebl==3)?136:164;
                c0 = smF[A0_EMB + toff + idx*4 + d0];
                c1 = smF[A0_EMB + toff + idx*4 + d0 + 1];
            }
            sm[A0_CAT + row*36 + j] = pack_h2f(c0, c1);
        }
        __syncthreads();

        // P1: h1 = tanh(cat @ Wd1^T + bd1)
        {
            f32x4 c1a[2];
            c1a[0] = (f32x4){bb10, bb10, bb10, bb10};
            c1a[1] = (f32x4){bb11, bb11, bb11, bb11};
            #pragma unroll
            for (int ks = 0; ks < 2; ++ks){
                uint4 a = *reinterpret_cast<const uint4*>(
                    sm + A0_CAT + (16*w + (l&15))*36 + ks*16 + 4*(l>>4));
                #pragma unroll
                for (int n = 0; n < 2; ++n)
                    c1a[n] = mfma16(a, *reinterpret_cast<const uint4*>(
                        sm + A0_WM + ((n*2 + ks)*64 + l)*4), c1a[n]);
            }
            #pragma unroll
            for (int n = 0; n < 2; ++n)
                #pragma unroll
                for (int j = 0; j < 4; ++j){
                    float v = fast_tanh(c1a[n][j]);
                    float vp = __shfl_xor(v, 1);
                    if (!(l & 1))
                        sm[A0_H1 + (16*w + 4*(l>>4) + j)*20 + 8*n + ((l&15) >> 1)] = pack_h2f(v, vp);
                }
        }
        wsync();

        // P2: sfe = tanh(h1 @ Wd2^T + bd2); feat = [attn*sfe | sfe]
        {
            uint4 a = *reinterpret_cast<const uint4*>(
                sm + A0_H1 + (16*w + (l&15))*20 + 4*(l>>4));
            f32x4 c2[4];
            c2[0] = (f32x4){bb20, bb20, bb20, bb20};
            c2[1] = (f32x4){bb21, bb21, bb21, bb21};
            c2[2] = (f32x4){bb22, bb22, bb22, bb22};
            c2[3] = (f32x4){bb23, bb23, bb23, bb23};
            #pragma unroll
            for (int n = 0; n < 4; ++n)
                c2[n] = mfma16(a, *reinterpret_cast<const uint4*>(
                    sm + A0_WM + ((4 + n)*64 + l)*4), c2[n]);
            #pragma unroll
            for (int n = 0; n < 4; ++n)
                #pragma unroll
                for (int j = 0; j < 4; ++j){
                    int row = 16*w + 4*(l>>4) + j;
                    int rel = (R0 + row >= eB) ? 1 : 0;
                    float s  = fast_tanh(c2[n][j]);
                    float fa = smF[A0_ATT + rel*64 + 16*n + (l&15)] * s;
                    float sp  = __shfl_xor(s, 1);
                    float fap = __shfl_xor(fa, 1);
                    if (!(l & 1)){
                        int ci = 8*n + ((l&15) >> 1);
                        sm[A0_FT + row*68 + ci]      = pack_h2f(fa, fap);
                        sm[A0_FT + row*68 + 32 + ci] = pack_h2f(s, sp);
                    }
                }
        }
        __syncthreads();

        // P3: xg = feat @ Wih0^T ; direct f16 stores
        #pragma unroll
        for (int m = 0; m < 4; ++m){
            uint4 af[4];
            #pragma unroll
            for (int ks = 0; ks < 4; ++ks)
                af[ks] = *reinterpret_cast<const uint4*>(
                    sm + A0_FT + (16*m + (l&15))*68 + ks*16 + 4*(l>>4));
            f32x4 acc[3];
            #pragma unroll
            for (int nn = 0; nn < 3; ++nn) acc[nn] = (f32x4){0.f, 0.f, 0.f, 0.f};
            #pragma unroll
            for (int ks = 0; ks < 4; ++ks)
                #pragma unroll
                for (int nn = 0; nn < 3; ++nn)
                    acc[nn] = mfma16(af[ks], bw[nn][ks], acc[nn]);
            #pragma unroll
            for (int nn = 0; nn < 3; ++nn)
                #pragma unroll
                for (int j = 0; j < 4; ++j){
                    size_t row = (size_t)R0 + 16*m + 4*(l>>4) + j;
                    xgout[row*192 + 16*(w + 4*nn) + (l&15)] = (_Float16)acc[nn][j];
                }
        }
    }
}

// ---------- kernel 4: persistent xg1 GEMM: out0 @ Wih1^T ----------
__global__ __launch_bounds__(256, 2)
void nbst_xg1(const unsigned* __restrict__ out0g, const float* __restrict__ Wih1,
              _Float16* __restrict__ xgout)
{
    __shared__ u32 sm[64*36];
    const int tid = threadIdx.x;
    const int w = tid >> 6, l = tid & 63;
    uint4 bw[3][2];
    #pragma unroll
    for (int nn = 0; nn < 3; ++nn)
        #pragma unroll
        for (int ks = 0; ks < 2; ++ks)
            bw[nn][ks] = load_bfrag(Wih1, 64, 16*(w + 4*nn) + (l&15), 32*ks + 8*(l>>4), 64);

    for (int tile = blockIdx.x; tile < NT_; tile += gridDim.x){
        const int R0 = tile * 64;
        for (int e = tid; e < 64*32; e += 256){
            int row = e >> 5, k = e & 31;
            sm[row*36 + k] = out0g[(size_t)(R0 + row)*32 + k];
        }
        __syncthreads();
        #pragma unroll
        for (int m = 0; m < 4; ++m){
            uint4 af[2];
            #pragma unroll
            for (int ks = 0; ks < 2; ++ks)
                af[ks] = *reinterpret_cast<const uint4*>(
                    sm + (16*m + (l&15))*36 + ks*16 + 4*(l>>4));
            f32x4 acc[3];
            #pragma unroll
            for (int nn = 0; nn < 3; ++nn) acc[nn] = (f32x4){0.f, 0.f, 0.f, 0.f};
            #pragma unroll
            for (int ks = 0; ks < 2; ++ks)
                #pragma unroll
                for (int nn = 0; nn < 3; ++nn)
                    acc[nn] = mfma16(af[ks], bw[nn][ks], acc[nn]);
            #pragma unroll
            for (int nn = 0; nn < 3; ++nn)
                #pragma unroll
                for (int j = 0; j < 4; ++j){
                    size_t row = (size_t)R0 + 16*m + 4*(l>>4) + j;
                    xgout[row*192 + 16*(w + 4*nn) + (l&15)] = (_Float16)acc[nn][j];
                }
        }
        __syncthreads();
    }
}

// ---------- recurrent kernels: SGPR h-broadcast, ZERO loop LDS / barriers ----------
// lane l produces h[l]; redistribution is intra-wave: cvt_pkrtz pair-pack +
// 32x v_readlane into SGPRs; v_dot2_f32_f16 consumes the SGPR as src0.

__global__ __launch_bounds__(256, 2)
void nbst_rec0l(const _Float16* __restrict__ xgh, const float* __restrict__ Whh0,
                const float* __restrict__ bih0, const float* __restrict__ bhh0,
                unsigned* __restrict__ out0g, float* __restrict__ hf0g)
{
    __shared__ u32 smr[192*36];
    const int tid = threadIdx.x, wv = tid >> 6, l = tid & 63;
    const int b = blockIdx.x * 4 + wv;
    for (int e = tid; e < 192*32; e += 256){
        int row = e >> 5, k = e & 31;
        smr[row*36 + k] = pack_h2f(Whh0[row*64 + 2*k], Whh0[row*64 + 2*k + 1]);
    }
    __syncthreads();

    u32 wr[32], wz[32], wn[32];
    {
        const u32* pr = smr + l*36;
        const u32* pz = smr + (64+l)*36;
        const u32* pn = smr + (128+l)*36;
        #pragma unroll
        for (int i = 0; i < 8; ++i){
            uint4 a = *(const uint4*)(pr + 4*i);
            wr[4*i] = a.x; wr[4*i+1] = a.y; wr[4*i+2] = a.z; wr[4*i+3] = a.w;
            uint4 c = *(const uint4*)(pz + 4*i);
            wz[4*i] = c.x; wz[4*i+1] = c.y; wz[4*i+2] = c.z; wz[4*i+3] = c.w;
            uint4 d = *(const uint4*)(pn + 4*i);
            wn[4*i] = d.x; wn[4*i+1] = d.y; wn[4*i+2] = d.z; wn[4*i+3] = d.w;
        }
    }
    #pragma unroll
    for (int i = 0; i < 32; ++i)
        asm volatile("" : "+v"(wr[i]), "+v"(wz[i]), "+v"(wn[i]));

    const float br  = bih0[l]      + bhh0[l];
    const float bz  = bih0[64+l]   + bhh0[64+l];
    const float bxn = bih0[128+l];
    const float bhn = bhh0[128+l];
    float hreg = 0.f;
    u32 hs[32];
    #pragma unroll
    for (int i = 0; i < 32; ++i) hs[i] = 0u;

    const size_t rb = (size_t)b * S_;
    const _Float16* x0 = xgh + rb*192;
    _Float16 xra = x0[l],     xza = x0[64+l],     xna = x0[128+l];
    _Float16 xrb = x0[192+l], xzb = x0[192+64+l], xnb = x0[192+128+l];

    #pragma unroll 1
    for (int t = 0; t < S_; ++t){
        float xr = (float)xra, xz = (float)xza, xn = (float)xna;
        xra = xrb; xza = xzb; xna = xnb;
        {   int tn = (t + 2 < S_) ? t + 2 : S_ - 1;
            const _Float16* q = xgh + (rb + tn)*192;
            xrb = q[l]; xzb = q[64+l]; xnb = q[128+l]; }
        float ar0=0,az0=0,an0=0,ar1=0,az1=0,an1=0;
        #pragma unroll
        for (int k = 0; k < 32; ++k){
            float& ar = (k & 1) ? ar1 : ar0;
            float& az = (k & 1) ? az1 : az0;
            float& an = (k & 1) ? an1 : an0;
            ar = dot2h(hs[k], wr[k], ar);
            az = dot2h(hs[k], wz[k], az);
            an = dot2h(hs[k], wn[k], an);
        }
        float rg = fast_sigmoid(xr + ar0 + ar1 + br);
        float zg = fast_sigmoid(xz + az0 + az1 + bz);
        float ng = fast_tanh(xn + bxn + rg*(an0 + an1 + bhn));
        hreg = (1.f - zg)*ng + zg*hreg;
        float hp2 = __shfl_xor(hreg, 1);
        u32 pk = __builtin_bit_cast(u32, __builtin_amdgcn_cvt_pkrtz(hreg, hp2));
        if (!(l & 1)) out0g[(rb + t)*32 + (l >> 1)] = pk;   // even lanes hold (h[l],h[l+1])
        #pragma unroll
        for (int i = 0; i < 32; ++i)
            hs[i] = (u32)__builtin_amdgcn_readlane((int)pk, 2*i);
    }
    hf0g[(size_t)b*64 + l] = hreg;
}

__global__ __launch_bounds__(256, 2)
void nbst_rec1l(const _Float16* __restrict__ xgh, const float* __restrict__ Whh1,
                const float* __restrict__ bih1, const float* __restrict__ bhh1,
                const float* __restrict__ hf0g,
                const float* __restrict__ Wpred, const float* __restrict__ bpred,
                float* __restrict__ outp)
{
    __shared__ u32 smr[192*36];
    const int tid = threadIdx.x, wv = tid >> 6, l = tid & 63;
    const int b = blockIdx.x * 4 + wv;
    for (int e = tid; e < 192*32; e += 256){
        int row = e >> 5, k = e & 31;
        smr[row*36 + k] = pack_h2f(Whh1[row*64 + 2*k], Whh1[row*64 + 2*k + 1]);
    }
    __syncthreads();

    u32 wr[32], wz[32], wn[32];
    {
        const u32* pr = smr + l*36;
        const u32* pz = smr + (64+l)*36;
        const u32* pn = smr + (128+l)*36;
        #pragma unroll
        for (int i = 0; i < 8; ++i){
            uint4 a = *(const uint4*)(pr + 4*i);
            wr[4*i] = a.x; wr[4*i+1] = a.y; wr[4*i+2] = a.z; wr[4*i+3] = a.w;
            uint4 c = *(const uint4*)(pz + 4*i);
            wz[4*i] = c.x; wz[4*i+1] = c.y; wz[4*i+2] = c.z; wz[4*i+3] = c.w;
            uint4 d = *(const uint4*)(pn + 4*i);
            wn[4*i] = d.x; wn[4*i+1] = d.y; wn[4*i+2] = d.z; wn[4*i+3] = d.w;
        }
    }
    #pragma unroll
    for (int i = 0; i < 32; ++i)
        asm volatile("" : "+v"(wr[i]), "+v"(wz[i]), "+v"(wn[i]));

    const float br  = bih1[l]      + bhh1[l];
    const float bz  = bih1[64+l]   + bhh1[64+l];
    const float bxn = bih1[128+l];
    const float bhn = bhh1[128+l];
    float hreg = 0.f;
    u32 hs[32];
    #pragma unroll
    for (int i = 0; i < 32; ++i) hs[i] = 0u;

    const size_t rb = (size_t)b * S_;
    const _Float16* x0 = xgh + rb*192;
    _Float16 xra = x0[l],     xza = x0[64+l],     xna = x0[128+l];
    _Float16 xrb = x0[192+l], xzb = x0[192+64+l], xnb = x0[192+128+l];

    #pragma unroll 1
    for (int t = 0; t < S_; ++t){
        float xr = (float)xra, xz = (float)xza, xn = (float)xna;
        xra = xrb; xza = xzb; xna = xnb;
        {   int tn = (t + 2 < S_) ? t + 2 : S_ - 1;
            const _Float16* q = xgh + (rb + tn)*192;
            xrb = q[l]; xzb = q[64+l]; xnb = q[128+l]; }
        float ar0=0,az0=0,an0=0,ar1=0,az1=0,an1=0;
        #pragma unroll
        for (int k = 0; k < 32; ++k){
            float& ar = (k & 1) ? ar1 : ar0;
            float& az = (k & 1) ? az1 : az0;
            float& an = (k & 1) ? an1 : an0;
            ar = dot2h(hs[k], wr[k], ar);
            az = dot2h(hs[k], wz[k], az);
            an = dot2h(hs[k], wn[k], an);
        }
        float rg = fast_sigmoid(xr + ar0 + ar1 + br);
        float zg = fast_sigmoid(xz + az0 + az1 + bz);
        float ng = fast_tanh(xn + bxn + rg*(an0 + an1 + bhn));
        hreg = (1.f - zg)*ng + zg*hreg;
        float hp2 = __shfl_xor(hreg, 1);
        u32 pk = __builtin_bit_cast(u32, __builtin_amdgcn_cvt_pkrtz(hreg, hp2));
        #pragma unroll
        for (int i = 0; i < 32; ++i)
            hs[i] = (u32)__builtin_amdgcn_readlane((int)pk, 2*i);
    }
    float hf0v = hf0g[(size_t)b*64 + l];
    float part = hf0v * Wpred[l] + hreg * Wpred[64 + l];
    #pragma unroll
    for (int s = 32; s >= 1; s >>= 1) part += __shfl_xor(part, s);
    if (l == 0) outp[b] = fast_tanh(part + bpred[0]);
}

// ---------- launcher ----------
extern "C" void kernel_launch(void* const* d_in, const int* in_sizes, int n_in,
                              void* d_out, int out_size, void* d_ws, size_t ws_size,
                              hipStream_t stream) {
    (void)in_sizes; (void)n_in; (void)out_size; (void)ws_size;
    const float* station_nodes    = (const float*)d_in[1];
    const float* station_features = (const float*)d_in[2];
    const int*   station_emb      = (const int*)d_in[3];
    const float* e0 = (const float*)d_in[4];
    const float* e1 = (const float*)d_in[5];
    const float* e2 = (const float*)d_in[6];
    const float* e3 = (const float*)d_in[7];
    const float* e4 = (const float*)d_in[8];
    const float* W_nodes = (const float*)d_in[9];
    const float* b_nodes = (const float*)d_in[10];
    const float* W_attn  = (const float*)d_in[11];
    const float* W_d1 = (const float*)d_in[13];
    const float* b_d1 = (const float*)d_in[14];
    const float* W_d2 = (const float*)d_in[15];
    const float* b_d2 = (const float*)d_in[16];
    const float* Wih0 = (const float*)d_in[17];
    const float* Whh0 = (const float*)d_in[18];
    const float* bih0 = (const float*)d_in[19];
    const float* bhh0 = (const float*)d_in[20];
    const float* Wih1 = (const float*)d_in[21];
    const float* Whh1 = (const float*)d_in[22];
    const float* bih1 = (const float*)d_in[23];
    const float* bhh1 = (const float*)d_in[24];
    const float* W_pred = (const float*)d_in[25];
    const float* b_pred = (const float*)d_in[26];
    float* outp = (float*)d_out;

    char* ws = (char*)d_ws;
    float*    attnW  = (float*)ws;                        // 512 KiB
    float*    hf0    = (float*)(ws + (1u<<19));           // 512 KiB
    unsigned* out0pk = (unsigned*)(ws + (1u<<20));        // B*S*32 u32 = 44 MB
    _Float16* xg16   = (_Float16*)(ws + (48u<<20));       // B*S*192 f16 = 132 MB
    const _Float16* xgh = (const _Float16*)xg16;

    nbst_attn<<<dim3(512), dim3(256), 0, stream>>>(station_nodes, W_nodes, b_nodes, W_attn, attnW);
    nbst_mlpxg0<<<dim3(768), dim3(256), 0, stream>>>(
        station_features, station_emb, e0, e1, e2, e3, e4,
        W_d1, b_d1, W_d2, b_d2, Wih0, attnW, xg16);
    nbst_rec0l<<<dim3(512), dim3(256), 0, stream>>>(xgh, Whh0, bih0, bhh0, out0pk, hf0);
    nbst_xg1<<<dim3(1024), dim3(256), 0, stream>>>(out0pk, Wih1, xg16);
    nbst_rec1l<<<dim3(512), dim3(256), 0, stream>>>(xgh, Whh1, bih1, bhh1, hf0, W_pred, b_pred, outp);
}

// Round 8
// 366.762 us; speedup vs baseline: 1.0463x; 1.0463x over previous
//
#include <hip/hip_runtime.h>
#include <cstdint>
#include <cstddef>

#define B_ 2048
#define S_ 168
#define NT_ 5376   // (B_*S_)/64 row-tiles

// ---------- helpers ----------
typedef _Float16 h2_t __attribute__((ext_vector_type(2)));
typedef _Float16 f16x8 __attribute__((ext_vector_type(8)));
typedef float f32x4 __attribute__((ext_vector_type(4)));
typedef unsigned int u32;

__device__ __forceinline__ float dot2h(unsigned a, unsigned b, float c){
    return __builtin_amdgcn_fdot2(__builtin_bit_cast(h2_t, a),
                                  __builtin_bit_cast(h2_t, b), c, false);
}
__device__ __forceinline__ unsigned pack_h2f(float a, float b){
    h2_t v; v.x = (_Float16)a; v.y = (_Float16)b;
    return __builtin_bit_cast(unsigned, v);
}
__device__ __forceinline__ float fast_exp(float x){
    return __builtin_amdgcn_exp2f(x * 1.44269504088896340736f);
}
__device__ __forceinline__ float fast_sigmoid(float x){
    return __builtin_amdgcn_rcpf(1.0f + fast_exp(-x));
}
__device__ __forceinline__ float fast_tanh(float x){
    return 1.0f - 2.0f * __builtin_amdgcn_rcpf(1.0f + fast_exp(2.0f * x));
}
__device__ __forceinline__ void wsync(){
    asm volatile("s_waitcnt lgkmcnt(0)" ::: "memory");
    __builtin_amdgcn_wave_barrier();
}
__device__ __forceinline__ f32x4 mfma16(uint4 a, uint4 b, f32x4 c){
    return __builtin_amdgcn_mfma_f32_16x16x32_f16(
        __builtin_bit_cast(f16x8, a), __builtin_bit_cast(f16x8, b), c, 0, 0, 0);
}
__device__ __forceinline__ uint4 load_bfrag(const float* __restrict__ W, int ldk,
                                            int o, int kk0, int kmax){
    float w[8];
    #pragma unroll
    for (int e = 0; e < 8; ++e){
        int kk = kk0 + e;
        w[e] = (kk < kmax) ? W[o*ldk + kk] : 0.f;
    }
    uint4 r;
    r.x = pack_h2f(w[0], w[1]); r.y = pack_h2f(w[2], w[3]);
    r.z = pack_h2f(w[4], w[5]); r.w = pack_h2f(w[6], w[7]);
    return r;
}
// Non-rematerializable register pin: the def of the result becomes an
// INLINEASM node (real v_mov), which LLVM can never rematerialize from the
// original LDS load -> value must stay VGPR-resident (or visibly spill).
__device__ __forceinline__ u32 pin_reg(u32 x){
    u32 y;
    asm volatile("v_mov_b32 %0, %1" : "=v"(y) : "v"(x));
    return y;
}

// ---------- kernel 1: attention over stations (proven) ----------
__global__ void nbst_attn(const float* __restrict__ sn, const float* __restrict__ Wn,
                          const float* __restrict__ bn, const float* __restrict__ Wa,
                          float* __restrict__ attnO){
    __shared__ float WnL[64*16];
    __shared__ float WsL[64];
    __shared__ float bnL[64];
    const int tid = threadIdx.x;
    for (int e = tid; e < 1024; e += 256) WnL[e] = Wn[e];
    if (tid < 64){ WsL[tid] = Wa[64 + tid]; bnL[tid] = bn[tid]; }
    __syncthreads();
    const int wv = tid >> 6, l = tid & 63;
    const int b = blockIdx.x * 4 + wv;
    const float* xp = sn + ((size_t)b * 64 + l) * 16;
    float x[16];
    #pragma unroll
    for (int k = 0; k < 16; ++k) x[k] = xp[k];
    float e_i = 0.f;
    for (int h = 0; h < 64; ++h){
        float acc = bnL[h];
        #pragma unroll
        for (int k = 0; k < 16; ++k) acc += x[k] * WnL[h*16 + k];
        e_i += fast_tanh(acc) * WsL[h];
    }
    float m = e_i;
    #pragma unroll
    for (int s = 32; s >= 1; s >>= 1) m = fmaxf(m, __shfl_xor(m, s));
    float p = fast_exp(e_i - m);
    float ssum = p;
    #pragma unroll
    for (int s = 32; s >= 1; s >>= 1) ssum += __shfl_xor(ssum, s);
    attnO[(size_t)b*64 + l] = p * __builtin_amdgcn_rcpf(ssum);
}

// ---------- kernel 2: persistent MLP + xg0 GEMM (proven) ----------
#define A0_CAT 0      // [64][36] u32: 0..17 cat pairs, 18..35 zero (K pad)
#define A0_H1  2304   // [64][20]
#define A0_FT  3584   // [64][68]
#define A0_WM  7936   // [8 frags][64 lanes][4]
#define A0_EMB 9984   // 260 f32
#define A0_ATT 10244  // 128 f32: attn rows b0, b0+1
#define A0_TOT 10372

__global__ __launch_bounds__(256, 2)
void nbst_mlpxg0(const float* __restrict__ sf, const int* __restrict__ se,
                 const float* __restrict__ e0, const float* __restrict__ e1,
                 const float* __restrict__ e2, const float* __restrict__ e3,
                 const float* __restrict__ e4,
                 const float* __restrict__ Wd1, const float* __restrict__ bd1,
                 const float* __restrict__ Wd2, const float* __restrict__ bd2,
                 const float* __restrict__ Wih0, const float* __restrict__ attnI,
                 _Float16* __restrict__ xgout)
{
    __shared__ u32 sm[A0_TOT];
    float* smF = reinterpret_cast<float*>(sm);
    const int tid = threadIdx.x;
    const int w = tid >> 6, l = tid & 63;

    // ---- one-time prologue ----
    for (int e = tid; e < 260; e += 256){
        float v;
        if (e < 48)       v = e0[e];
        else if (e < 88)  v = e1[e-48];
        else if (e < 136) v = e2[e-88];
        else if (e < 164) v = e3[e-136];
        else              v = e4[e-164];
        smF[A0_EMB + e] = v;
    }
    for (int f = w; f < 8; f += 4){
        uint4 fr;
        if (f < 4){ int n = f >> 1, ks = f & 1;
                    fr = load_bfrag(Wd1, 36, 16*n + (l&15), 32*ks + 8*(l>>4), 36); }
        else      { int n = f - 4;
                    fr = load_bfrag(Wd2, 32, 16*n + (l&15), 8*(l>>4), 32); }
        *reinterpret_cast<uint4*>(sm + A0_WM + (f*64 + l)*4) = fr;
    }
    uint4 bw[3][4];
    #pragma unroll
    for (int nn = 0; nn < 3; ++nn)
        #pragma unroll
        for (int ks = 0; ks < 4; ++ks)
            bw[nn][ks] = load_bfrag(Wih0, 128, 16*(w + 4*nn) + (l&15), 32*ks + 8*(l>>4), 128);
    for (int e = tid; e < 64*18; e += 256){           // zero CAT K-pad once
        int row = e / 18, j = 18 + e % 18;
        sm[A0_CAT + row*36 + j] = 0u;
    }
    const float bb10 = bd1[(l&15)],  bb11 = bd1[16+(l&15)];
    const float bb20 = bd2[(l&15)],  bb21 = bd2[16+(l&15)];
    const float bb22 = bd2[32+(l&15)], bb23 = bd2[48+(l&15)];
    __syncthreads();

    // ---- persistent tile loop ----
    for (int tile = blockIdx.x; tile < NT_; tile += gridDim.x){
        const int R0 = tile * 64;
        const int b0 = R0 / S_;
        const int eB = (b0 + 1) * S_;
        if (tid < 128){
            int bi = b0 + (tid >> 6); if (bi >= B_) bi = B_ - 1;
            smF[A0_ATT + tid] = attnI[(size_t)bi*64 + (tid & 63)];
        }
        for (int e = tid; e < 64*18; e += 256){
            int row = e / 18, j = e % 18;
            int R = R0 + row;
            float c0, c1;
            if (j < 8){
                c0 = sf[(size_t)R*16 + 2*j]; c1 = sf[(size_t)R*16 + 2*j + 1];
            } else {
                int jj = j - 8, ebl = jj >> 1, d0 = (jj & 1) * 2;
                int idx = se[(size_t)R*5 + ebl] - (ebl >= 2 ? 1 : 0);
                const int toff = (ebl==0)?0:(ebl==1)?48:(ebl==2)?88:(ebl==3)?136:164;
                c0 = smF[A0_EMB + toff + idx*4 + d0];
                c1 = smF[A0_EMB + toff + idx*4 + d0 + 1];
            }
            sm[A0_CAT + row*36 + j] = pack_h2f(c0, c1);
        }
        __syncthreads();

        // P1: h1 = tanh(cat @ Wd1^T + bd1)
        {
            f32x4 c1a[2];
            c1a[0] = (f32x4){bb10, bb10, bb10, bb10};
            c1a[1] = (f32x4){bb11, bb11, bb11, bb11};
            #pragma unroll
            for (int ks = 0; ks < 2; ++ks){
                uint4 a = *reinterpret_cast<const uint4*>(
                    sm + A0_CAT + (16*w + (l&15))*36 + ks*16 + 4*(l>>4));
                #pragma unroll
                for (int n = 0; n < 2; ++n)
                    c1a[n] = mfma16(a, *reinterpret_cast<const uint4*>(
                        sm + A0_WM + ((n*2 + ks)*64 + l)*4), c1a[n]);
            }
            #pragma unroll
            for (int n = 0; n < 2; ++n)
                #pragma unroll
                for (int j = 0; j < 4; ++j){
                    float v = fast_tanh(c1a[n][j]);
                    float vp = __shfl_xor(v, 1);
                    if (!(l & 1))
                        sm[A0_H1 + (16*w + 4*(l>>4) + j)*20 + 8*n + ((l&15) >> 1)] = pack_h2f(v, vp);
                }
        }
        wsync();

        // P2: sfe = tanh(h1 @ Wd2^T + bd2); feat = [attn*sfe | sfe]
        {
            uint4 a = *reinterpret_cast<const uint4*>(
                sm + A0_H1 + (16*w + (l&15))*20 + 4*(l>>4));
            f32x4 c2[4];
            c2[0] = (f32x4){bb20, bb20, bb20, bb20};
            c2[1] = (f32x4){bb21, bb21, bb21, bb21};
            c2[2] = (f32x4){bb22, bb22, bb22, bb22};
            c2[3] = (f32x4){bb23, bb23, bb23, bb23};
            #pragma unroll
            for (int n = 0; n < 4; ++n)
                c2[n] = mfma16(a, *reinterpret_cast<const uint4*>(
                    sm + A0_WM + ((4 + n)*64 + l)*4), c2[n]);
            #pragma unroll
            for (int n = 0; n < 4; ++n)
                #pragma unroll
                for (int j = 0; j < 4; ++j){
                    int row = 16*w + 4*(l>>4) + j;
                    int rel = (R0 + row >= eB) ? 1 : 0;
                    float s  = fast_tanh(c2[n][j]);
                    float fa = smF[A0_ATT + rel*64 + 16*n + (l&15)] * s;
                    float sp  = __shfl_xor(s, 1);
                    float fap = __shfl_xor(fa, 1);
                    if (!(l & 1)){
                        int ci = 8*n + ((l&15) >> 1);
                        sm[A0_FT + row*68 + ci]      = pack_h2f(fa, fap);
                        sm[A0_FT + row*68 + 32 + ci] = pack_h2f(s, sp);
                    }
                }
        }
        __syncthreads();

        // P3: xg = feat @ Wih0^T ; direct f16 stores
        #pragma unroll
        for (int m = 0; m < 4; ++m){
            uint4 af[4];
            #pragma unroll
            for (int ks = 0; ks < 4; ++ks)
                af[ks] = *reinterpret_cast<const uint4*>(
                    sm + A0_FT + (16*m + (l&15))*68 + ks*16 + 4*(l>>4));
            f32x4 acc[3];
            #pragma unroll
            for (int nn = 0; nn < 3; ++nn) acc[nn] = (f32x4){0.f, 0.f, 0.f, 0.f};
            #pragma unroll
            for (int ks = 0; ks < 4; ++ks)
                #pragma unroll
                for (int nn = 0; nn < 3; ++nn)
                    acc[nn] = mfma16(af[ks], bw[nn][ks], acc[nn]);
            #pragma unroll
            for (int nn = 0; nn < 3; ++nn)
                #pragma unroll
                for (int j = 0; j < 4; ++j){
                    size_t row = (size_t)R0 + 16*m + 4*(l>>4) + j;
                    xgout[row*192 + 16*(w + 4*nn) + (l&15)] = (_Float16)acc[nn][j];
                }
        }
    }
}

// ---------- kernel 4: persistent xg1 GEMM: out0 @ Wih1^T ----------
__global__ __launch_bounds__(256, 2)
void nbst_xg1(const unsigned* __restrict__ out0g, const float* __restrict__ Wih1,
              _Float16* __restrict__ xgout)
{
    __shared__ u32 sm[64*36];
    const int tid = threadIdx.x;
    const int w = tid >> 6, l = tid & 63;
    uint4 bw[3][2];
    #pragma unroll
    for (int nn = 0; nn < 3; ++nn)
        #pragma unroll
        for (int ks = 0; ks < 2; ++ks)
            bw[nn][ks] = load_bfrag(Wih1, 64, 16*(w + 4*nn) + (l&15), 32*ks + 8*(l>>4), 64);

    for (int tile = blockIdx.x; tile < NT_; tile += gridDim.x){
        const int R0 = tile * 64;
        for (int e = tid; e < 64*32; e += 256){
            int row = e >> 5, k = e & 31;
            sm[row*36 + k] = out0g[(size_t)(R0 + row)*32 + k];
        }
        __syncthreads();
        #pragma unroll
        for (int m = 0; m < 4; ++m){
            uint4 af[2];
            #pragma unroll
            for (int ks = 0; ks < 2; ++ks)
                af[ks] = *reinterpret_cast<const uint4*>(
                    sm + (16*m + (l&15))*36 + ks*16 + 4*(l>>4));
            f32x4 acc[3];
            #pragma unroll
            for (int nn = 0; nn < 3; ++nn) acc[nn] = (f32x4){0.f, 0.f, 0.f, 0.f};
            #pragma unroll
            for (int ks = 0; ks < 2; ++ks)
                #pragma unroll
                for (int nn = 0; nn < 3; ++nn)
                    acc[nn] = mfma16(af[ks], bw[nn][ks], acc[nn]);
            #pragma unroll
            for (int nn = 0; nn < 3; ++nn)
                #pragma unroll
                for (int j = 0; j < 4; ++j){
                    size_t row = (size_t)R0 + 16*m + 4*(l>>4) + j;
                    xgout[row*192 + 16*(w + 4*nn) + (l&15)] = (_Float16)acc[nn][j];
                }
        }
        __syncthreads();
    }
}

// ---------- recurrent kernels: v_mov-pinned weight registers ----------
#define RW_HP 6912    // per-wave h pairs, stride 40

__global__ __launch_bounds__(256, 2)
void nbst_rec0l(const _Float16* __restrict__ xgh, const float* __restrict__ Whh0,
                const float* __restrict__ bih0, const float* __restrict__ bhh0,
                unsigned* __restrict__ out0g, float* __restrict__ hf0g)
{
    __shared__ u32 smr[RW_HP + 4*40];
    const int tid = threadIdx.x, wv = tid >> 6, l = tid & 63;
    const int b = blockIdx.x * 4 + wv;
    for (int e = tid; e < 192*32; e += 256){
        int row = e >> 5, k = e & 31;
        smr[row*36 + k] = pack_h2f(Whh0[row*64 + 2*k], Whh0[row*64 + 2*k + 1]);
    }
    u32* HP = smr + RW_HP + wv*40;
    if (l < 32) HP[l] = 0u;
    __syncthreads();

    u32 wr[32], wz[32], wn[32];
    {
        const u32* pr = smr + l*36;
        const u32* pz = smr + (64+l)*36;
        const u32* pn = smr + (128+l)*36;
        #pragma unroll
        for (int i = 0; i < 8; ++i){
            uint4 a = *(const uint4*)(pr + 4*i);
            wr[4*i] = a.x; wr[4*i+1] = a.y; wr[4*i+2] = a.z; wr[4*i+3] = a.w;
            uint4 c = *(const uint4*)(pz + 4*i);
            wz[4*i] = c.x; wz[4*i+1] = c.y; wz[4*i+2] = c.z; wz[4*i+3] = c.w;
            uint4 d = *(const uint4*)(pn + 4*i);
            wn[4*i] = d.x; wn[4*i+1] = d.y; wn[4*i+2] = d.z; wn[4*i+3] = d.w;
        }
    }
    #pragma unroll
    for (int i = 0; i < 32; ++i){
        wr[i] = pin_reg(wr[i]);
        wz[i] = pin_reg(wz[i]);
        wn[i] = pin_reg(wn[i]);
    }

    const float br  = bih0[l]      + bhh0[l];
    const float bz  = bih0[64+l]   + bhh0[64+l];
    const float bxn = bih0[128+l];
    const float bhn = bhh0[128+l];
    float hreg = 0.f;
    const size_t rb = (size_t)b * S_;
    const _Float16* x0 = xgh + rb*192;
    _Float16 xra = x0[l],     xza = x0[64+l],     xna = x0[128+l];
    _Float16 xrb = x0[192+l], xzb = x0[192+64+l], xnb = x0[192+128+l];
    wsync();

    #pragma unroll 1
    for (int t = 0; t < S_; ++t){
        float xr = (float)xra, xz = (float)xza, xn = (float)xna;
        xra = xrb; xza = xzb; xna = xnb;
        {   int tn = (t + 2 < S_) ? t + 2 : S_ - 1;
            const _Float16* q = xgh + (rb + tn)*192;
            xrb = q[l]; xzb = q[64+l]; xnb = q[128+l]; }
        uint4 h0 = *(const uint4*)(HP+0);  uint4 h1 = *(const uint4*)(HP+4);
        uint4 h2 = *(const uint4*)(HP+8);  uint4 h3 = *(const uint4*)(HP+12);
        uint4 h4 = *(const uint4*)(HP+16); uint4 h5 = *(const uint4*)(HP+20);
        uint4 h6 = *(const uint4*)(HP+24); uint4 h7 = *(const uint4*)(HP+28);
        float ar0=0,az0=0,an0=0,ar1=0,az1=0,an1=0;
        ar0 = dot2h(h0.x, wr[0], ar0); ar0 = dot2h(h0.y, wr[1], ar0);
        ar0 = dot2h(h0.z, wr[2], ar0); ar0 = dot2h(h0.w, wr[3], ar0);
        az0 = dot2h(h0.x, wz[0], az0); az0 = dot2h(h0.y, wz[1], az0);
        az0 = dot2h(h0.z, wz[2], az0); az0 = dot2h(h0.w, wz[3], az0);
        an0 = dot2h(h0.x, wn[0], an0); an0 = dot2h(h0.y, wn[1], an0);
        an0 = dot2h(h0.z, wn[2], an0); an0 = dot2h(h0.w, wn[3], an0);
        ar1 = dot2h(h1.x, wr[4], ar1); ar1 = dot2h(h1.y, wr[5], ar1);
        ar1 = dot2h(h1.z, wr[6], ar1); ar1 = dot2h(h1.w, wr[7], ar1);
        az1 = dot2h(h1.x, wz[4], az1); az1 = dot2h(h1.y, wz[5], az1);
        az1 = dot2h(h1.z, wz[6], az1); az1 = dot2h(h1.w, wz[7], az1);
        an1 = dot2h(h1.x, wn[4], an1); an1 = dot2h(h1.y, wn[5], an1);
        an1 = dot2h(h1.z, wn[6], an1); an1 = dot2h(h1.w, wn[7], an1);
        ar0 = dot2h(h2.x, wr[8], ar0); ar0 = dot2h(h2.y, wr[9], ar0);
        ar0 = dot2h(h2.z, wr[10], ar0); ar0 = dot2h(h2.w, wr[11], ar0);
        az0 = dot2h(h2.x, wz[8], az0); az0 = dot2h(h2.y, wz[9], az0);
        az0 = dot2h(h2.z, wz[10], az0); az0 = dot2h(h2.w, wz[11], az0);
        an0 = dot2h(h2.x, wn[8], an0); an0 = dot2h(h2.y, wn[9], an0);
        an0 = dot2h(h2.z, wn[10], an0); an0 = dot2h(h2.w, wn[11], an0);
        ar1 = dot2h(h3.x, wr[12], ar1); ar1 = dot2h(h3.y, wr[13], ar1);
        ar1 = dot2h(h3.z, wr[14], ar1); ar1 = dot2h(h3.w, wr[15], ar1);
        az1 = dot2h(h3.x, wz[12], az1); az1 = dot2h(h3.y, wz[13], az1);
        az1 = dot2h(h3.z, wz[14], az1); az1 = dot2h(h3.w, wz[15], az1);
        an1 = dot2h(h3.x, wn[12], an1); an1 = dot2h(h3.y, wn[13], an1);
        an1 = dot2h(h3.z, wn[14], an1); an1 = dot2h(h3.w, wn[15], an1);
        ar0 = dot2h(h4.x, wr[16], ar0); ar0 = dot2h(h4.y, wr[17], ar0);
        ar0 = dot2h(h4.z, wr[18], ar0); ar0 = dot2h(h4.w, wr[19], ar0);
        az0 = dot2h(h4.x, wz[16], az0); az0 = dot2h(h4.y, wz[17], az0);
        az0 = dot2h(h4.z, wz[18], az0); az0 = dot2h(h4.w, wz[19], az0);
        an0 = dot2h(h4.x, wn[16], an0); an0 = dot2h(h4.y, wn[17], an0);
        an0 = dot2h(h4.z, wn[18], an0); an0 = dot2h(h4.w, wn[19], an0);
        ar1 = dot2h(h5.x, wr[20], ar1); ar1 = dot2h(h5.y, wr[21], ar1);
        ar1 = dot2h(h5.z, wr[22], ar1); ar1 = dot2h(h5.w, wr[23], ar1);
        az1 = dot2h(h5.x, wz[20], az1); az1 = dot2h(h5.y, wz[21], az1);
        az1 = dot2h(h5.z, wz[22], az1); az1 = dot2h(h5.w, wz[23], az1);
        an1 = dot2h(h5.x, wn[20], an1); an1 = dot2h(h5.y, wn[21], an1);
        an1 = dot2h(h5.z, wn[22], an1); an1 = dot2h(h5.w, wn[23], an1);
        ar0 = dot2h(h6.x, wr[24], ar0); ar0 = dot2h(h6.y, wr[25], ar0);
        ar0 = dot2h(h6.z, wr[26], ar0); ar0 = dot2h(h6.w, wr[27], ar0);
        az0 = dot2h(h6.x, wz[24], az0); az0 = dot2h(h6.y, wz[25], az0);
        az0 = dot2h(h6.z, wz[26], az0); az0 = dot2h(h6.w, wz[27], az0);
        an0 = dot2h(h6.x, wn[24], an0); an0 = dot2h(h6.y, wn[25], an0);
        an0 = dot2h(h6.z, wn[26], an0); an0 = dot2h(h6.w, wn[27], an0);
        ar1 = dot2h(h7.x, wr[28], ar1); ar1 = dot2h(h7.y, wr[29], ar1);
        ar1 = dot2h(h7.z, wr[30], ar1); ar1 = dot2h(h7.w, wr[31], ar1);
        az1 = dot2h(h7.x, wz[28], az1); az1 = dot2h(h7.y, wz[29], az1);
        az1 = dot2h(h7.z, wz[30], az1); az1 = dot2h(h7.w, wz[31], az1);
        an1 = dot2h(h7.x, wn[28], an1); an1 = dot2h(h7.y, wn[29], an1);
        an1 = dot2h(h7.z, wn[30], an1); an1 = dot2h(h7.w, wn[31], an1);
        float rg = fast_sigmoid(xr + ar0 + ar1 + br);
        float zg = fast_sigmoid(xz + az0 + az1 + bz);
        float ng = fast_tanh(xn + bxn + rg*(an0 + an1 + bhn));
        hreg = (1.f - zg)*ng + zg*hreg;
        float hp2 = __shfl_xor(hreg, 1);
        if (!(l & 1)){
            unsigned hu = pack_h2f(hreg, hp2);
            HP[l >> 1] = hu;
            out0g[(rb + t)*32 + (l >> 1)] = hu;
        }
        wsync();
    }
    hf0g[(size_t)b*64 + l] = hreg;
}

__global__ __launch_bounds__(256, 2)
void nbst_rec1l(const _Float16* __restrict__ xgh, const float* __restrict__ Whh1,
                const float* __restrict__ bih1, const float* __restrict__ bhh1,
                const float* __restrict__ hf0g,
                const float* __restrict__ Wpred, const float* __restrict__ bpred,
                float* __restrict__ outp)
{
    __shared__ u32 smr[RW_HP + 4*40];
    const int tid = threadIdx.x, wv = tid >> 6, l = tid & 63;
    const int b = blockIdx.x * 4 + wv;
    for (int e = tid; e < 192*32; e += 256){
        int row = e >> 5, k = e & 31;
        smr[row*36 + k] = pack_h2f(Whh1[row*64 + 2*k], Whh1[row*64 + 2*k + 1]);
    }
    u32* HP = smr + RW_HP + wv*40;
    if (l < 32) HP[l] = 0u;
    __syncthreads();

    u32 wr[32], wz[32], wn[32];
    {
        const u32* pr = smr + l*36;
        const u32* pz = smr + (64+l)*36;
        const u32* pn = smr + (128+l)*36;
        #pragma unroll
        for (int i = 0; i < 8; ++i){
            uint4 a = *(const uint4*)(pr + 4*i);
            wr[4*i] = a.x; wr[4*i+1] = a.y; wr[4*i+2] = a.z; wr[4*i+3] = a.w;
            uint4 c = *(const uint4*)(pz + 4*i);
            wz[4*i] = c.x; wz[4*i+1] = c.y; wz[4*i+2] = c.z; wz[4*i+3] = c.w;
            uint4 d = *(const uint4*)(pn + 4*i);
            wn[4*i] = d.x; wn[4*i+1] = d.y; wn[4*i+2] = d.z; wn[4*i+3] = d.w;
        }
    }
    #pragma unroll
    for (int i = 0; i < 32; ++i){
        wr[i] = pin_reg(wr[i]);
        wz[i] = pin_reg(wz[i]);
        wn[i] = pin_reg(wn[i]);
    }

    const float br  = bih1[l]      + bhh1[l];
    const float bz  = bih1[64+l]   + bhh1[64+l];
    const float bxn = bih1[128+l];
    const float bhn = bhh1[128+l];
    float hreg = 0.f;
    const size_t rb = (size_t)b * S_;
    const _Float16* x0 = xgh + rb*192;
    _Float16 xra = x0[l],     xza = x0[64+l],     xna = x0[128+l];
    _Float16 xrb = x0[192+l], xzb = x0[192+64+l], xnb = x0[192+128+l];
    wsync();

    #pragma unroll 1
    for (int t = 0; t < S_; ++t){
        float xr = (float)xra, xz = (float)xza, xn = (float)xna;
        xra = xrb; xza = xzb; xna = xnb;
        {   int tn = (t + 2 < S_) ? t + 2 : S_ - 1;
            const _Float16* q = xgh + (rb + tn)*192;
            xrb = q[l]; xzb = q[64+l]; xnb = q[128+l]; }
        uint4 h0 = *(const uint4*)(HP+0);  uint4 h1 = *(const uint4*)(HP+4);
        uint4 h2 = *(const uint4*)(HP+8);  uint4 h3 = *(const uint4*)(HP+12);
        uint4 h4 = *(const uint4*)(HP+16); uint4 h5 = *(const uint4*)(HP+20);
        uint4 h6 = *(const uint4*)(HP+24); uint4 h7 = *(const uint4*)(HP+28);
        float ar0=0,az0=0,an0=0,ar1=0,az1=0,an1=0;
        ar0 = dot2h(h0.x, wr[0], ar0); ar0 = dot2h(h0.y, wr[1], ar0);
        ar0 = dot2h(h0.z, wr[2], ar0); ar0 = dot2h(h0.w, wr[3], ar0);
        az0 = dot2h(h0.x, wz[0], az0); az0 = dot2h(h0.y, wz[1], az0);
        az0 = dot2h(h0.z, wz[2], az0); az0 = dot2h(h0.w, wz[3], az0);
        an0 = dot2h(h0.x, wn[0], an0); an0 = dot2h(h0.y, wn[1], an0);
        an0 = dot2h(h0.z, wn[2], an0); an0 = dot2h(h0.w, wn[3], an0);
        ar1 = dot2h(h1.x, wr[4], ar1); ar1 = dot2h(h1.y, wr[5], ar1);
        ar1 = dot2h(h1.z, wr[6], ar1); ar1 = dot2h(h1.w, wr[7], ar1);
        az1 = dot2h(h1.x, wz[4], az1); az1 = dot2h(h1.y, wz[5], az1);
        az1 = dot2h(h1.z, wz[6], az1); az1 = dot2h(h1.w, wz[7], az1);
        an1 = dot2h(h1.x, wn[4], an1); an1 = dot2h(h1.y, wn[5], an1);
        an1 = dot2h(h1.z, wn[6], an1); an1 = dot2h(h1.w, wn[7], an1);
        ar0 = dot2h(h2.x, wr[8], ar0); ar0 = dot2h(h2.y, wr[9], ar0);
        ar0 = dot2h(h2.z, wr[10], ar0); ar0 = dot2h(h2.w, wr[11], ar0);
        az0 = dot2h(h2.x, wz[8], az0); az0 = dot2h(h2.y, wz[9], az0);
        az0 = dot2h(h2.z, wz[10], az0); az0 = dot2h(h2.w, wz[11], az0);
        an0 = dot2h(h2.x, wn[8], an0); an0 = dot2h(h2.y, wn[9], an0);
        an0 = dot2h(h2.z, wn[10], an0); an0 = dot2h(h2.w, wn[11], an0);
        ar1 = dot2h(h3.x, wr[12], ar1); ar1 = dot2h(h3.y, wr[13], ar1);
        ar1 = dot2h(h3.z, wr[14], ar1); ar1 = dot2h(h3.w, wr[15], ar1);
        az1 = dot2h(h3.x, wz[12], az1); az1 = dot2h(h3.y, wz[13], az1);
        az1 = dot2h(h3.z, wz[14], az1); az1 = dot2h(h3.w, wz[15], az1);
        an1 = dot2h(h3.x, wn[12], an1); an1 = dot2h(h3.y, wn[13], an1);
        an1 = dot2h(h3.z, wn[14], an1); an1 = dot2h(h3.w, wn[15], an1);
        ar0 = dot2h(h4.x, wr[16], ar0); ar0 = dot2h(h4.y, wr[17], ar0);
        ar0 = dot2h(h4.z, wr[18], ar0); ar0 = dot2h(h4.w, wr[19], ar0);
        az0 = dot2h(h4.x, wz[16], az0); az0 = dot2h(h4.y, wz[17], az0);
        az0 = dot2h(h4.z, wz[18], az0); az0 = dot2h(h4.w, wz[19], az0);
        an0 = dot2h(h4.x, wn[16], an0); an0 = dot2h(h4.y, wn[17], an0);
        an0 = dot2h(h4.z, wn[18], an0); an0 = dot2h(h4.w, wn[19], an0);
        ar1 = dot2h(h5.x, wr[20], ar1); ar1 = dot2h(h5.y, wr[21], ar1);
        ar1 = dot2h(h5.z, wr[22], ar1); ar1 = dot2h(h5.w, wr[23], ar1);
        az1 = dot2h(h5.x, wz[20], az1); az1 = dot2h(h5.y, wz[21], az1);
        az1 = dot2h(h5.z, wz[22], az1); az1 = dot2h(h5.w, wz[23], az1);
        an1 = dot2h(h5.x, wn[20], an1); an1 = dot2h(h5.y, wn[21], an1);
        an1 = dot2h(h5.z, wn[22], an1); an1 = dot2h(h5.w, wn[23], an1);
        ar0 = dot2h(h6.x, wr[24], ar0); ar0 = dot2h(h6.y, wr[25], ar0);
        ar0 = dot2h(h6.z, wr[26], ar0); ar0 = dot2h(h6.w, wr[27], ar0);
        az0 = dot2h(h6.x, wz[24], az0); az0 = dot2h(h6.y, wz[25], az0);
        az0 = dot2h(h6.z, wz[26], az0); az0 = dot2h(h6.w, wz[27], az0);
        an0 = dot2h(h6.x, wn[24], an0); an0 = dot2h(h6.y, wn[25], an0);
        an0 = dot2h(h6.z, wn[26], an0); an0 = dot2h(h6.w, wn[27], an0);
        ar1 = dot2h(h7.x, wr[28], ar1); ar1 = dot2h(h7.y, wr[29], ar1);
        ar1 = dot2h(h7.z, wr[30], ar1); ar1 = dot2h(h7.w, wr[31], ar1);
        az1 = dot2h(h7.x, wz[28], az1); az1 = dot2h(h7.y, wz[29], az1);
        az1 = dot2h(h7.z, wz[30], az1); az1 = dot2h(h7.w, wz[31], az1);
        an1 = dot2h(h7.x, wn[28], an1); an1 = dot2h(h7.y, wn[29], an1);
        an1 = dot2h(h7.z, wn[30], an1); an1 = dot2h(h7.w, wn[31], an1);
        float rg = fast_sigmoid(xr + ar0 + ar1 + br);
        float zg = fast_sigmoid(xz + az0 + az1 + bz);
        float ng = fast_tanh(xn + bxn + rg*(an0 + an1 + bhn));
        hreg = (1.f - zg)*ng + zg*hreg;
        float hp2 = __shfl_xor(hreg, 1);
        if (!(l & 1)) HP[l >> 1] = pack_h2f(hreg, hp2);
        wsync();
    }
    float hf0v = hf0g[(size_t)b*64 + l];
    float part = hf0v * Wpred[l] + hreg * Wpred[64 + l];
    #pragma unroll
    for (int s = 32; s >= 1; s >>= 1) part += __shfl_xor(part, s);
    if (l == 0) outp[b] = fast_tanh(part + bpred[0]);
}

// ---------- launcher ----------
extern "C" void kernel_launch(void* const* d_in, const int* in_sizes, int n_in,
                              void* d_out, int out_size, void* d_ws, size_t ws_size,
                              hipStream_t stream) {
    (void)in_sizes; (void)n_in; (void)out_size; (void)ws_size;
    const float* station_nodes    = (const float*)d_in[1];
    const float* station_features = (const float*)d_in[2];
    const int*   station_emb      = (const int*)d_in[3];
    const float* e0 = (const float*)d_in[4];
    const float* e1 = (const float*)d_in[5];
    const float* e2 = (const float*)d_in[6];
    const float* e3 = (const float*)d_in[7];
    const float* e4 = (const float*)d_in[8];
    const float* W_nodes = (const float*)d_in[9];
    const float* b_nodes = (const float*)d_in[10];
    const float* W_attn  = (const float*)d_in[11];
    const float* W_d1 = (const float*)d_in[13];
    const float* b_d1 = (const float*)d_in[14];
    const float* W_d2 = (const float*)d_in[15];
    const float* b_d2 = (const float*)d_in[16];
    const float* Wih0 = (const float*)d_in[17];
    const float* Whh0 = (const float*)d_in[18];
    const float* bih0 = (const float*)d_in[19];
    const float* bhh0 = (const float*)d_in[20];
    const float* Wih1 = (const float*)d_in[21];
    const float* Whh1 = (const float*)d_in[22];
    const float* bih1 = (const float*)d_in[23];
    const float* bhh1 = (const float*)d_in[24];
    const float* W_pred = (const float*)d_in[25];
    const float* b_pred = (const float*)d_in[26];
    float* outp = (float*)d_out;

    char* ws = (char*)d_ws;
    float*    attnW  = (float*)ws;                        // 512 KiB
    float*    hf0    = (float*)(ws + (1u<<19));           // 512 KiB
    unsigned* out0pk = (unsigned*)(ws + (1u<<20));        // B*S*32 u32 = 44 MB
    _Float16* xg16   = (_Float16*)(ws + (48u<<20));       // B*S*192 f16 = 132 MB
    const _Float16* xgh = (const _Float16*)xg16;

    nbst_attn<<<dim3(512), dim3(256), 0, stream>>>(station_nodes, W_nodes, b_nodes, W_attn, attnW);
    nbst_mlpxg0<<<dim3(768), dim3(256), 0, stream>>>(
        station_features, station_emb, e0, e1, e2, e3, e4,
        W_d1, b_d1, W_d2, b_d2, Wih0, attnW, xg16);
    nbst_rec0l<<<dim3(512), dim3(256), 0, stream>>>(xgh, Whh0, bih0, bhh0, out0pk, hf0);
    nbst_xg1<<<dim3(1024), dim3(256), 0, stream>>>(out0pk, Wih1, xg16);
    nbst_rec1l<<<dim3(512), dim3(256), 0, stream>>>(xgh, Whh1, bih1, bhh1, hf0, W_pred, b_pred, outp);
}

// Round 9
// 297.010 us; speedup vs baseline: 1.2920x; 1.2348x over previous
//
#include <hip/hip_runtime.h>
#include <cstdint>
#include <cstddef>

#define B_ 2048
#define S_ 168
#define NT_ 5376   // 128 groups x 42 t-tiles

// ---------- helpers ----------
typedef _Float16 h2_t __attribute__((ext_vector_type(2)));
typedef _Float16 f16x8 __attribute__((ext_vector_type(8)));
typedef float f32x4 __attribute__((ext_vector_type(4)));
typedef unsigned int u32;

__device__ __forceinline__ unsigned pack_h2f(float a, float b){
    h2_t v; v.x = (_Float16)a; v.y = (_Float16)b;
    return __builtin_bit_cast(unsigned, v);
}
__device__ __forceinline__ float fast_exp(float x){
    return __builtin_amdgcn_exp2f(x * 1.44269504088896340736f);
}
__device__ __forceinline__ float fast_sigmoid(float x){
    return __builtin_amdgcn_rcpf(1.0f + fast_exp(-x));
}
__device__ __forceinline__ float fast_tanh(float x){
    return 1.0f - 2.0f * __builtin_amdgcn_rcpf(1.0f + fast_exp(2.0f * x));
}
__device__ __forceinline__ void wsync(){
    asm volatile("s_waitcnt lgkmcnt(0)" ::: "memory");
    __builtin_amdgcn_wave_barrier();
}
__device__ __forceinline__ f32x4 mfma16(uint4 a, uint4 b, f32x4 c){
    return __builtin_amdgcn_mfma_f32_16x16x32_f16(
        __builtin_bit_cast(f16x8, a), __builtin_bit_cast(f16x8, b), c, 0, 0, 0);
}
__device__ __forceinline__ uint4 load_bfrag(const float* __restrict__ W, int ldk,
                                            int o, int kk0, int kmax){
    float w[8];
    #pragma unroll
    for (int e = 0; e < 8; ++e){
        int kk = kk0 + e;
        w[e] = (kk < kmax) ? W[o*ldk + kk] : 0.f;
    }
    uint4 r;
    r.x = pack_h2f(w[0], w[1]); r.y = pack_h2f(w[2], w[3]);
    r.z = pack_h2f(w[4], w[5]); r.w = pack_h2f(w[6], w[7]);
    return r;
}

// ---------- kernel 1: attention over stations (proven) ----------
__global__ void nbst_attn(const float* __restrict__ sn, const float* __restrict__ Wn,
                          const float* __restrict__ bn, const float* __restrict__ Wa,
                          float* __restrict__ attnO){
    __shared__ float WnL[64*16];
    __shared__ float WsL[64];
    __shared__ float bnL[64];
    const int tid = threadIdx.x;
    for (int e = tid; e < 1024; e += 256) WnL[e] = Wn[e];
    if (tid < 64){ WsL[tid] = Wa[64 + tid]; bnL[tid] = bn[tid]; }
    __syncthreads();
    const int wv = tid >> 6, l = tid & 63;
    const int b = blockIdx.x * 4 + wv;
    const float* xp = sn + ((size_t)b * 64 + l) * 16;
    float x[16];
    #pragma unroll
    for (int k = 0; k < 16; ++k) x[k] = xp[k];
    float e_i = 0.f;
    for (int h = 0; h < 64; ++h){
        float acc = bnL[h];
        #pragma unroll
        for (int k = 0; k < 16; ++k) acc += x[k] * WnL[h*16 + k];
        e_i += fast_tanh(acc) * WsL[h];
    }
    float m = e_i;
    #pragma unroll
    for (int s = 32; s >= 1; s >>= 1) m = fmaxf(m, __shfl_xor(m, s));
    float p = fast_exp(e_i - m);
    float ssum = p;
    #pragma unroll
    for (int s = 32; s >= 1; s >>= 1) ssum += __shfl_xor(ssum, s);
    attnO[(size_t)b*64 + l] = p * __builtin_amdgcn_rcpf(ssum);
}

// ---------- kernel 2: persistent MLP -> feat A-frags ----------
// tile = (gb, tb): 64 rows = 16 batch rows (16gb..16gb+15) x 4 times (4tb..4tb+3).
// m-tile w covers all 16 b at t=4tb+w; its A-frags go straight to featF.
#define A0_CAT 0      // [64][36] u32
#define A0_H1  2304   // [64][20]
#define A0_FT  3584   // [64][68]
#define A0_WM  7936   // [8 frags][64 lanes][4]
#define A0_EMB 9984   // 260 f32
#define A0_ATT 10244  // 1024 f32: attn rows 16gb..16gb+15
#define A0_TOT 11268

__global__ __launch_bounds__(256, 2)
void nbst_mlpxg0(const float* __restrict__ sf, const int* __restrict__ se,
                 const float* __restrict__ e0, const float* __restrict__ e1,
                 const float* __restrict__ e2, const float* __restrict__ e3,
                 const float* __restrict__ e4,
                 const float* __restrict__ Wd1, const float* __restrict__ bd1,
                 const float* __restrict__ Wd2, const float* __restrict__ bd2,
                 const float* __restrict__ attnI,
                 u32* __restrict__ featF)
{
    __shared__ u32 sm[A0_TOT];
    float* smF = reinterpret_cast<float*>(sm);
    const int tid = threadIdx.x;
    const int w = tid >> 6, l = tid & 63;
    const int q = l >> 4, c = l & 15;

    for (int e = tid; e < 260; e += 256){
        float v;
        if (e < 48)       v = e0[e];
        else if (e < 88)  v = e1[e-48];
        else if (e < 136) v = e2[e-88];
        else if (e < 164) v = e3[e-136];
        else              v = e4[e-164];
        smF[A0_EMB + e] = v;
    }
    for (int f = w; f < 8; f += 4){
        uint4 fr;
        if (f < 4){ int n = f >> 1, ks = f & 1;
                    fr = load_bfrag(Wd1, 36, 16*n + c, 32*ks + 8*q, 36); }
        else      { int n = f - 4;
                    fr = load_bfrag(Wd2, 32, 16*n + c, 8*q, 32); }
        *reinterpret_cast<uint4*>(sm + A0_WM + (f*64 + l)*4) = fr;
    }
    for (int e = tid; e < 64*18; e += 256){           // zero CAT K-pad once
        int row = e / 18, j = 18 + e % 18;
        sm[A0_CAT + row*36 + j] = 0u;
    }
    const float bb10 = bd1[c],  bb11 = bd1[16+c];
    const float bb20 = bd2[c],  bb21 = bd2[16+c];
    const float bb22 = bd2[32+c], bb23 = bd2[48+c];
    __syncthreads();

    for (int tile = blockIdx.x; tile < NT_; tile += gridDim.x){
        const int gb = tile / 42, tb = tile % 42;
        // stage attn rows for the 16 batch rows (contiguous)
        for (int e = tid; e < 1024; e += 256)
            smF[A0_ATT + e] = attnI[(size_t)(16*gb)*64 + e];
        // build cat
        for (int e = tid; e < 64*18; e += 256){
            int row = e / 18, j = e % 18;
            int R = (16*gb + (row & 15))*S_ + 4*tb + (row >> 4);
            float c0, c1;
            if (j < 8){
                c0 = sf[(size_t)R*16 + 2*j]; c1 = sf[(size_t)R*16 + 2*j + 1];
            } else {
                int jj = j - 8, ebl = jj >> 1, d0 = (jj & 1) * 2;
                int idx = se[(size_t)R*5 + ebl] - (ebl >= 2 ? 1 : 0);
                const int toff = (ebl==0)?0:(ebl==1)?48:(ebl==2)?88:(ebl==3)?136:164;
                c0 = smF[A0_EMB + toff + idx*4 + d0];
                c1 = smF[A0_EMB + toff + idx*4 + d0 + 1];
            }
            sm[A0_CAT + row*36 + j] = pack_h2f(c0, c1);
        }
        __syncthreads();

        // P1: h1 = tanh(cat @ Wd1^T + bd1)
        {
            f32x4 c1a[2];
            c1a[0] = (f32x4){bb10, bb10, bb10, bb10};
            c1a[1] = (f32x4){bb11, bb11, bb11, bb11};
            #pragma unroll
            for (int ks = 0; ks < 2; ++ks){
                uint4 a = *reinterpret_cast<const uint4*>(
                    sm + A0_CAT + (16*w + c)*36 + ks*16 + 4*q);
                #pragma unroll
                for (int n = 0; n < 2; ++n)
                    c1a[n] = mfma16(a, *reinterpret_cast<const uint4*>(
                        sm + A0_WM + ((n*2 + ks)*64 + l)*4), c1a[n]);
            }
            #pragma unroll
            for (int n = 0; n < 2; ++n)
                #pragma unroll
                for (int j = 0; j < 4; ++j){
                    float v = fast_tanh(c1a[n][j]);
                    float vp = __shfl_xor(v, 1);
                    if (!(l & 1))
                        sm[A0_H1 + (16*w + 4*q + j)*20 + 8*n + (c >> 1)] = pack_h2f(v, vp);
                }
        }
        wsync();

        // P2: sfe = tanh(h1 @ Wd2^T + bd2); feat = [attn*sfe | sfe]
        {
            uint4 a = *reinterpret_cast<const uint4*>(
                sm + A0_H1 + (16*w + c)*20 + 4*q);
            f32x4 c2[4];
            c2[0] = (f32x4){bb20, bb20, bb20, bb20};
            c2[1] = (f32x4){bb21, bb21, bb21, bb21};
            c2[2] = (f32x4){bb22, bb22, bb22, bb22};
            c2[3] = (f32x4){bb23, bb23, bb23, bb23};
            #pragma unroll
            for (int n = 0; n < 4; ++n)
                c2[n] = mfma16(a, *reinterpret_cast<const uint4*>(
                    sm + A0_WM + ((4 + n)*64 + l)*4), c2[n]);
            #pragma unroll
            for (int n = 0; n < 4; ++n)
                #pragma unroll
                for (int j = 0; j < 4; ++j){
                    float s  = fast_tanh(c2[n][j]);
                    float fa = smF[A0_ATT + (4*q + j)*64 + 16*n + c] * s;
                    float sp  = __shfl_xor(s, 1);
                    float fap = __shfl_xor(fa, 1);
                    if (!(l & 1)){
                        int row = 16*w + 4*q + j;
                        int ci = 8*n + (c >> 1);
                        sm[A0_FT + row*68 + ci]      = pack_h2f(fa, fap);
                        sm[A0_FT + row*68 + 32 + ci] = pack_h2f(s, sp);
                    }
                }
        }
        wsync();   // wave w reads only its own FT rows below

        // P3': store A-frags of feat (wave w = time 4tb+w) straight to global
        {
            const int t = 4*tb + w;
            size_t base = ((size_t)(gb*S_ + t))*1024;
            #pragma unroll
            for (int ks = 0; ks < 4; ++ks){
                uint4 af = *reinterpret_cast<const uint4*>(
                    sm + A0_FT + (16*w + c)*68 + ks*16 + 4*q);
                *reinterpret_cast<uint4*>(featF + base + ks*256 + l*4) = af;
            }
        }
        __syncthreads();   // before next tile's CAT/ATT overwrite
    }
}

// ---------- kernel 3: GRU layer 0, MFMA recurrence ----------
// block = 16 batch rows; wave w owns h-cols 16w..16w+15 (gate tiles w, 4+w, 8+w).
// K-concat [feat(128) | h(64)]: ks0..3 feat (global A-frags), ks4..5 h (LDS).
__global__ __launch_bounds__(256, 1)
void nbst_rec0m(const u32* __restrict__ featF,
                const float* __restrict__ Wih0, const float* __restrict__ Whh0,
                const float* __restrict__ bih0, const float* __restrict__ bhh0,
                u32* __restrict__ out0F, float* __restrict__ hf0g)
{
    extern __shared__ u32 sm[];
    u32* smw  = sm;            // [192][100] packed [Wih0 | Whh0] pairs
    u32* hbuf = sm + 19200;    // [16][32] u32, XOR-swizzled
    const int tid = threadIdx.x, w = tid >> 6, l = tid & 63;
    const int q = l >> 4, c = l & 15;
    const int g = blockIdx.x, B0 = g*16;

    for (int e = tid; e < 192*96; e += 256){
        int row = e / 96, kp = e % 96;
        smw[row*100 + kp] = (kp < 64)
            ? pack_h2f(Wih0[row*128 + 2*kp],      Wih0[row*128 + 2*kp + 1])
            : pack_h2f(Whh0[row*64 + 2*(kp-64)],  Whh0[row*64 + 2*(kp-64) + 1]);
    }
    hbuf[tid] = 0u; hbuf[tid + 256] = 0u;
    __syncthreads();

    const int gr = 16*w + c, gz = 64 + 16*w + c, gn = 128 + 16*w + c;
    uint4 bR[6], bZ[6], bXN[4], bHN[2];
    #pragma unroll
    for (int ks = 0; ks < 6; ++ks){
        bR[ks] = *reinterpret_cast<const uint4*>(smw + gr*100 + 16*ks + 4*q);
        bZ[ks] = *reinterpret_cast<const uint4*>(smw + gz*100 + 16*ks + 4*q);
    }
    #pragma unroll
    for (int ks = 0; ks < 4; ++ks)
        bXN[ks] = *reinterpret_cast<const uint4*>(smw + gn*100 + 16*ks + 4*q);
    bHN[0] = *reinterpret_cast<const uint4*>(smw + gn*100 + 64 + 4*q);
    bHN[1] = *reinterpret_cast<const uint4*>(smw + gn*100 + 80 + 4*q);

    const float br  = bih0[gr] + bhh0[gr];
    const float bz  = bih0[gz] + bhh0[gz];
    const float bxn = bih0[gn];
    const float bhn = bhh0[gn];

    // swizzled h A-frag read indices: row=c, halfs 8q+32ks'
    const int rd0 = (c*32 + 4*q)      ^ ((c & 7) << 2);
    const int rd1 = (c*32 + 4*q + 16) ^ ((c & 7) << 2);
    int wri[4];
    #pragma unroll
    for (int j = 0; j < 4; ++j){
        int row = 4*q + j;
        wri[j] = (row*32 + 8*w + (c >> 1)) ^ ((row & 7) << 2);
    }

    const u32* fbase = featF + (size_t)g * S_ * 1024;
    u32* obase = out0F + (size_t)g * S_ * 512;
    uint4 fA0, fA1, fA2, fA3, fB0, fB1, fB2, fB3;
    fA0 = *reinterpret_cast<const uint4*>(fbase + 0*256 + l*4);
    fA1 = *reinterpret_cast<const uint4*>(fbase + 1*256 + l*4);
    fA2 = *reinterpret_cast<const uint4*>(fbase + 2*256 + l*4);
    fA3 = *reinterpret_cast<const uint4*>(fbase + 3*256 + l*4);
    float h0r = 0.f, h1r = 0.f, h2r = 0.f, h3r = 0.f;
    __syncthreads();

    #pragma unroll 1
    for (int t = 0; t < S_; ++t){
        {   // prefetch feat(t+1)
            int tn = (t + 1 < S_) ? t + 1 : t;
            const u32* fp = fbase + (size_t)tn * 1024;
            fB0 = *reinterpret_cast<const uint4*>(fp + 0*256 + l*4);
            fB1 = *reinterpret_cast<const uint4*>(fp + 1*256 + l*4);
            fB2 = *reinterpret_cast<const uint4*>(fp + 2*256 + l*4);
            fB3 = *reinterpret_cast<const uint4*>(fp + 3*256 + l*4);
        }
        uint4 hA0 = *reinterpret_cast<const uint4*>(hbuf + rd0);
        uint4 hA1 = *reinterpret_cast<const uint4*>(hbuf + rd1);
        if (t > 0){   // these ARE out0[t-1] A-frags
            u32* op = obase + (size_t)(t - 1) * 512;
            *reinterpret_cast<uint4*>(op + l*4)       = hA0;
            *reinterpret_cast<uint4*>(op + 256 + l*4) = hA1;
        }
        f32x4 aR = {0,0,0,0}, aZ = {0,0,0,0}, aXN = {0,0,0,0}, aHN = {0,0,0,0};
        aR  = mfma16(fA0, bR[0], aR);  aR  = mfma16(fA1, bR[1], aR);
        aR  = mfma16(fA2, bR[2], aR);  aR  = mfma16(fA3, bR[3], aR);
        aZ  = mfma16(fA0, bZ[0], aZ);  aZ  = mfma16(fA1, bZ[1], aZ);
        aZ  = mfma16(fA2, bZ[2], aZ);  aZ  = mfma16(fA3, bZ[3], aZ);
        aXN = mfma16(fA0, bXN[0], aXN); aXN = mfma16(fA1, bXN[1], aXN);
        aXN = mfma16(fA2, bXN[2], aXN); aXN = mfma16(fA3, bXN[3], aXN);
        aR  = mfma16(hA0, bR[4], aR);  aR  = mfma16(hA1, bR[5], aR);
        aZ  = mfma16(hA0, bZ[4], aZ);  aZ  = mfma16(hA1, bZ[5], aZ);
        aHN = mfma16(hA0, bHN[0], aHN); aHN = mfma16(hA1, bHN[1], aHN);
        {
            float rg, zg, ng;
            rg = fast_sigmoid(aR[0] + br); zg = fast_sigmoid(aZ[0] + bz);
            ng = fast_tanh(aXN[0] + bxn + rg*(aHN[0] + bhn));
            h0r = (1.f - zg)*ng + zg*h0r;
            rg = fast_sigmoid(aR[1] + br); zg = fast_sigmoid(aZ[1] + bz);
            ng = fast_tanh(aXN[1] + bxn + rg*(aHN[1] + bhn));
            h1r = (1.f - zg)*ng + zg*h1r;
            rg = fast_sigmoid(aR[2] + br); zg = fast_sigmoid(aZ[2] + bz);
            ng = fast_tanh(aXN[2] + bxn + rg*(aHN[2] + bhn));
            h2r = (1.f - zg)*ng + zg*h2r;
            rg = fast_sigmoid(aR[3] + br); zg = fast_sigmoid(aZ[3] + bz);
            ng = fast_tanh(aXN[3] + bxn + rg*(aHN[3] + bhn));
            h3r = (1.f - zg)*ng + zg*h3r;
        }
        __syncthreads();   // all reads of h(t-1) done
        {
            float p0 = __shfl_xor(h0r, 1), p1 = __shfl_xor(h1r, 1);
            float p2 = __shfl_xor(h2r, 1), p3 = __shfl_xor(h3r, 1);
            if (!(c & 1)){
                hbuf[wri[0]] = pack_h2f(h0r, p0);
                hbuf[wri[1]] = pack_h2f(h1r, p1);
                hbuf[wri[2]] = pack_h2f(h2r, p2);
                hbuf[wri[3]] = pack_h2f(h3r, p3);
            }
        }
        __syncthreads();   // h(t) visible
        fA0 = fB0; fA1 = fB1; fA2 = fB2; fA3 = fB3;
    }
    {   // out0[167]
        uint4 hA0 = *reinterpret_cast<const uint4*>(hbuf + rd0);
        uint4 hA1 = *reinterpret_cast<const uint4*>(hbuf + rd1);
        u32* op = obase + (size_t)(S_ - 1) * 512;
        *reinterpret_cast<uint4*>(op + l*4)       = hA0;
        *reinterpret_cast<uint4*>(op + 256 + l*4) = hA1;
    }
    hf0g[(size_t)(B0 + 4*q + 0)*64 + 16*w + c] = h0r;
    hf0g[(size_t)(B0 + 4*q + 1)*64 + 16*w + c] = h1r;
    hf0g[(size_t)(B0 + 4*q + 2)*64 + 16*w + c] = h2r;
    hf0g[(size_t)(B0 + 4*q + 3)*64 + 16*w + c] = h3r;
}

// ---------- kernel 4: GRU layer 1 (fused xg1) + pred ----------
// K-concat [out0(64) | h1(64)]: ks0..1 out0 (global A-frags from rec0), ks2..3 h1.
__global__ __launch_bounds__(256, 1)
void nbst_rec1m(const u32* __restrict__ out0F,
                const float* __restrict__ Wih1, const float* __restrict__ Whh1,
                const float* __restrict__ bih1, const float* __restrict__ bhh1,
                const float* __restrict__ hf0g,
                const float* __restrict__ Wpred, const float* __restrict__ bpred,
                float* __restrict__ outp)
{
    extern __shared__ u32 sm[];
    u32* smw  = sm;            // [192][68] packed [Wih1 | Whh1] pairs
    u32* hbuf = sm + 13056;
    const int tid = threadIdx.x, w = tid >> 6, l = tid & 63;
    const int q = l >> 4, c = l & 15;
    const int g = blockIdx.x, B0 = g*16;

    for (int e = tid; e < 192*64; e += 256){
        int row = e / 64, kp = e % 64;
        smw[row*68 + kp] = (kp < 32)
            ? pack_h2f(Wih1[row*64 + 2*kp],       Wih1[row*64 + 2*kp + 1])
            : pack_h2f(Whh1[row*64 + 2*(kp-32)],  Whh1[row*64 + 2*(kp-32) + 1]);
    }
    hbuf[tid] = 0u; hbuf[tid + 256] = 0u;
    __syncthreads();

    const int gr = 16*w + c, gz = 64 + 16*w + c, gn = 128 + 16*w + c;
    uint4 bR[4], bZ[4], bXN[2], bHN[2];
    #pragma unroll
    for (int ks = 0; ks < 4; ++ks){
        bR[ks] = *reinterpret_cast<const uint4*>(smw + gr*68 + 16*ks + 4*q);
        bZ[ks] = *reinterpret_cast<const uint4*>(smw + gz*68 + 16*ks + 4*q);
    }
    bXN[0] = *reinterpret_cast<const uint4*>(smw + gn*68 +      4*q);
    bXN[1] = *reinterpret_cast<const uint4*>(smw + gn*68 + 16 + 4*q);
    bHN[0] = *reinterpret_cast<const uint4*>(smw + gn*68 + 32 + 4*q);
    bHN[1] = *reinterpret_cast<const uint4*>(smw + gn*68 + 48 + 4*q);

    const float br  = bih1[gr] + bhh1[gr];
    const float bz  = bih1[gz] + bhh1[gz];
    const float bxn = bih1[gn];
    const float bhn = bhh1[gn];

    const int rd0 = (c*32 + 4*q)      ^ ((c & 7) << 2);
    const int rd1 = (c*32 + 4*q + 16) ^ ((c & 7) << 2);
    int wri[4];
    #pragma unroll
    for (int j = 0; j < 4; ++j){
        int row = 4*q + j;
        wri[j] = (row*32 + 8*w + (c >> 1)) ^ ((row & 7) << 2);
    }

    const u32* obase = out0F + (size_t)g * S_ * 512;
    uint4 oA0, oA1, oB0, oB1;
    oA0 = *reinterpret_cast<const uint4*>(obase + 0*256 + l*4);
    oA1 = *reinterpret_cast<const uint4*>(obase + 1*256 + l*4);
    float h0r = 0.f, h1r = 0.f, h2r = 0.f, h3r = 0.f;
    __syncthreads();

    #pragma unroll 1
    for (int t = 0; t < S_; ++t){
        {   int tn = (t + 1 < S_) ? t + 1 : t;
            const u32* op = obase + (size_t)tn * 512;
            oB0 = *reinterpret_cast<const uint4*>(op + l*4);
            oB1 = *reinterpret_cast<const uint4*>(op + 256 + l*4);
        }
        uint4 hA0 = *reinterpret_cast<const uint4*>(hbuf + rd0);
        uint4 hA1 = *reinterpret_cast<const uint4*>(hbuf + rd1);
        f32x4 aR = {0,0,0,0}, aZ = {0,0,0,0}, aXN = {0,0,0,0}, aHN = {0,0,0,0};
        aR  = mfma16(oA0, bR[0], aR);  aR  = mfma16(oA1, bR[1], aR);
        aZ  = mfma16(oA0, bZ[0], aZ);  aZ  = mfma16(oA1, bZ[1], aZ);
        aXN = mfma16(oA0, bXN[0], aXN); aXN = mfma16(oA1, bXN[1], aXN);
        aR  = mfma16(hA0, bR[2], aR);  aR  = mfma16(hA1, bR[3], aR);
        aZ  = mfma16(hA0, bZ[2], aZ);  aZ  = mfma16(hA1, bZ[3], aZ);
        aHN = mfma16(hA0, bHN[0], aHN); aHN = mfma16(hA1, bHN[1], aHN);
        {
            float rg, zg, ng;
            rg = fast_sigmoid(aR[0] + br); zg = fast_sigmoid(aZ[0] + bz);
            ng = fast_tanh(aXN[0] + bxn + rg*(aHN[0] + bhn));
            h0r = (1.f - zg)*ng + zg*h0r;
            rg = fast_sigmoid(aR[1] + br); zg = fast_sigmoid(aZ[1] + bz);
            ng = fast_tanh(aXN[1] + bxn + rg*(aHN[1] + bhn));
            h1r = (1.f - zg)*ng + zg*h1r;
            rg = fast_sigmoid(aR[2] + br); zg = fast_sigmoid(aZ[2] + bz);
            ng = fast_tanh(aXN[2] + bxn + rg*(aHN[2] + bhn));
            h2r = (1.f - zg)*ng + zg*h2r;
            rg = fast_sigmoid(aR[3] + br); zg = fast_sigmoid(aZ[3] + bz);
            ng = fast_tanh(aXN[3] + bxn + rg*(aHN[3] + bhn));
            h3r = (1.f - zg)*ng + zg*h3r;
        }
        __syncthreads();
        {
            float p0 = __shfl_xor(h0r, 1), p1 = __shfl_xor(h1r, 1);
            float p2 = __shfl_xor(h2r, 1), p3 = __shfl_xor(h3r, 1);
            if (!(c & 1)){
                hbuf[wri[0]] = pack_h2f(h0r, p0);
                hbuf[wri[1]] = pack_h2f(h1r, p1);
                hbuf[wri[2]] = pack_h2f(h2r, p2);
                hbuf[wri[3]] = pack_h2f(h3r, p3);
            }
        }
        __syncthreads();
        oA0 = oB0; oA1 = oB1;
    }
    // pred head: thread tau = r*16+cg handles cols 4cg..4cg+3 of batch row B0+r
    {
        const int r = tid >> 4, cg = tid & 15;
        const int ia = (r*32 + 2*cg)     ^ ((r & 7) << 2);
        const int ib = (r*32 + 2*cg + 1) ^ ((r & 7) << 2);
        h2_t va = __builtin_bit_cast(h2_t, hbuf[ia]);
        h2_t vb = __builtin_bit_cast(h2_t, hbuf[ib]);
        const float* hp = hf0g + (size_t)(B0 + r)*64 + 4*cg;
        const float* wp0 = Wpred + 4*cg;
        const float* wp1 = Wpred + 64 + 4*cg;
        float part = hp[0]*wp0[0] + hp[1]*wp0[1] + hp[2]*wp0[2] + hp[3]*wp0[3]
                   + (float)va.x*wp1[0] + (float)va.y*wp1[1]
                   + (float)vb.x*wp1[2] + (float)vb.y*wp1[3];
        part += __shfl_xor(part, 8);
        part += __shfl_xor(part, 4);
        part += __shfl_xor(part, 2);
        part += __shfl_xor(part, 1);
        if (cg == 0) outp[B0 + r] = fast_tanh(part + bpred[0]);
    }
}

// ---------- launcher ----------
extern "C" void kernel_launch(void* const* d_in, const int* in_sizes, int n_in,
                              void* d_out, int out_size, void* d_ws, size_t ws_size,
                              hipStream_t stream) {
    (void)in_sizes; (void)n_in; (void)out_size; (void)ws_size;
    const float* station_nodes    = (const float*)d_in[1];
    const float* station_features = (const float*)d_in[2];
    const int*   station_emb      = (const int*)d_in[3];
    const float* e0 = (const float*)d_in[4];
    const float* e1 = (const float*)d_in[5];
    const float* e2 = (const float*)d_in[6];
    const float* e3 = (const float*)d_in[7];
    const float* e4 = (const float*)d_in[8];
    const float* W_nodes = (const float*)d_in[9];
    const float* b_nodes = (const float*)d_in[10];
    const float* W_attn  = (const float*)d_in[11];
    const float* W_d1 = (const float*)d_in[13];
    const float* b_d1 = (const float*)d_in[14];
    const float* W_d2 = (const float*)d_in[15];
    const float* b_d2 = (const float*)d_in[16];
    const float* Wih0 = (const float*)d_in[17];
    const float* Whh0 = (const float*)d_in[18];
    const float* bih0 = (const float*)d_in[19];
    const float* bhh0 = (const float*)d_in[20];
    const float* Wih1 = (const float*)d_in[21];
    const float* Whh1 = (const float*)d_in[22];
    const float* bih1 = (const float*)d_in[23];
    const float* bhh1 = (const float*)d_in[24];
    const float* W_pred = (const float*)d_in[25];
    const float* b_pred = (const float*)d_in[26];
    float* outp = (float*)d_out;

    char* ws = (char*)d_ws;
    float* attnW = (float*)ws;                     // 512 KiB
    float* hf0   = (float*)(ws + (1u<<19));        // 512 KiB
    u32*   out0F = (u32*)(ws + (1u<<20));          // 128*168*512 u32 = 42 MB
    u32*   featF = (u32*)(ws + (48u<<20));         // 128*168*1024 u32 = 84 MB

    hipFuncSetAttribute((const void*)nbst_rec0m,
                        hipFuncAttributeMaxDynamicSharedMemorySize, 80*1024);
    hipFuncSetAttribute((const void*)nbst_rec1m,
                        hipFuncAttributeMaxDynamicSharedMemorySize, 56*1024);

    nbst_attn<<<dim3(512), dim3(256), 0, stream>>>(station_nodes, W_nodes, b_nodes, W_attn, attnW);
    nbst_mlpxg0<<<dim3(768), dim3(256), 0, stream>>>(
        station_features, station_emb, e0, e1, e2, e3, e4,
        W_d1, b_d1, W_d2, b_d2, attnW, featF);
    nbst_rec0m<<<dim3(128), dim3(256), (19200 + 512)*4, stream>>>(
        featF, Wih0, Whh0, bih0, bhh0, out0F, hf0);
    nbst_rec1m<<<dim3(128), dim3(256), (13056 + 512)*4, stream>>>(
        out0F, Wih1, Whh1, bih1, bhh1, hf0, W_pred, b_pred, outp);
}

// Round 10
// 270.639 us; speedup vs baseline: 1.4179x; 1.0974x over previous
//
#include <hip/hip_runtime.h>
#include <cstdint>
#include <cstddef>

#define B_ 2048
#define S_ 168
#define NT_ 5376   // 128 groups x 42 t-tiles

// ---------- helpers ----------
typedef _Float16 h2_t __attribute__((ext_vector_type(2)));
typedef _Float16 f16x8 __attribute__((ext_vector_type(8)));
typedef float f32x4 __attribute__((ext_vector_type(4)));
typedef unsigned int u32;

__device__ __forceinline__ unsigned pack_h2f(float a, float b){
    h2_t v; v.x = (_Float16)a; v.y = (_Float16)b;
    return __builtin_bit_cast(unsigned, v);
}
__device__ __forceinline__ float fast_exp(float x){
    return __builtin_amdgcn_exp2f(x * 1.44269504088896340736f);
}
__device__ __forceinline__ float fast_sigmoid(float x){
    return __builtin_amdgcn_rcpf(1.0f + fast_exp(-x));
}
__device__ __forceinline__ float fast_tanh(float x){
    return 1.0f - 2.0f * __builtin_amdgcn_rcpf(1.0f + fast_exp(2.0f * x));
}
__device__ __forceinline__ void wsync(){
    asm volatile("s_waitcnt lgkmcnt(0)" ::: "memory");
    __builtin_amdgcn_wave_barrier();
}
// block barrier WITHOUT the vmcnt(0) drain __syncthreads() would emit:
// LDS ops ordered (lgkmcnt), global prefetch loads stay in flight.
__device__ __forceinline__ void bar_lds(){
    asm volatile("s_waitcnt lgkmcnt(0)\n\ts_barrier" ::: "memory");
}
__device__ __forceinline__ f32x4 mfma16(uint4 a, uint4 b, f32x4 c){
    return __builtin_amdgcn_mfma_f32_16x16x32_f16(
        __builtin_bit_cast(f16x8, a), __builtin_bit_cast(f16x8, b), c, 0, 0, 0);
}
__device__ __forceinline__ uint4 load_bfrag(const float* __restrict__ W, int ldk,
                                            int o, int kk0, int kmax){
    float w[8];
    #pragma unroll
    for (int e = 0; e < 8; ++e){
        int kk = kk0 + e;
        w[e] = (kk < kmax) ? W[o*ldk + kk] : 0.f;
    }
    uint4 r;
    r.x = pack_h2f(w[0], w[1]); r.y = pack_h2f(w[2], w[3]);
    r.z = pack_h2f(w[4], w[5]); r.w = pack_h2f(w[6], w[7]);
    return r;
}

// ---------- kernel 1: attention over stations (proven) ----------
__global__ void nbst_attn(const float* __restrict__ sn, const float* __restrict__ Wn,
                          const float* __restrict__ bn, const float* __restrict__ Wa,
                          float* __restrict__ attnO){
    __shared__ float WnL[64*16];
    __shared__ float WsL[64];
    __shared__ float bnL[64];
    const int tid = threadIdx.x;
    for (int e = tid; e < 1024; e += 256) WnL[e] = Wn[e];
    if (tid < 64){ WsL[tid] = Wa[64 + tid]; bnL[tid] = bn[tid]; }
    __syncthreads();
    const int wv = tid >> 6, l = tid & 63;
    const int b = blockIdx.x * 4 + wv;
    const float* xp = sn + ((size_t)b * 64 + l) * 16;
    float x[16];
    #pragma unroll
    for (int k = 0; k < 16; ++k) x[k] = xp[k];
    float e_i = 0.f;
    for (int h = 0; h < 64; ++h){
        float acc = bnL[h];
        #pragma unroll
        for (int k = 0; k < 16; ++k) acc += x[k] * WnL[h*16 + k];
        e_i += fast_tanh(acc) * WsL[h];
    }
    float m = e_i;
    #pragma unroll
    for (int s = 32; s >= 1; s >>= 1) m = fmaxf(m, __shfl_xor(m, s));
    float p = fast_exp(e_i - m);
    float ssum = p;
    #pragma unroll
    for (int s = 32; s >= 1; s >>= 1) ssum += __shfl_xor(ssum, s);
    attnO[(size_t)b*64 + l] = p * __builtin_amdgcn_rcpf(ssum);
}

// ---------- kernel 2: persistent MLP -> feat A-frags (proven round 9) ----------
#define A0_CAT 0      // [64][36] u32
#define A0_H1  2304   // [64][20]
#define A0_FT  3584   // [64][68]
#define A0_WM  7936   // [8 frags][64 lanes][4]
#define A0_EMB 9984   // 260 f32
#define A0_ATT 10244  // 1024 f32: attn rows 16gb..16gb+15
#define A0_TOT 11268

__global__ __launch_bounds__(256, 2)
void nbst_mlpxg0(const float* __restrict__ sf, const int* __restrict__ se,
                 const float* __restrict__ e0, const float* __restrict__ e1,
                 const float* __restrict__ e2, const float* __restrict__ e3,
                 const float* __restrict__ e4,
                 const float* __restrict__ Wd1, const float* __restrict__ bd1,
                 const float* __restrict__ Wd2, const float* __restrict__ bd2,
                 const float* __restrict__ attnI,
                 u32* __restrict__ featF)
{
    __shared__ u32 sm[A0_TOT];
    float* smF = reinterpret_cast<float*>(sm);
    const int tid = threadIdx.x;
    const int w = tid >> 6, l = tid & 63;
    const int q = l >> 4, c = l & 15;

    for (int e = tid; e < 260; e += 256){
        float v;
        if (e < 48)       v = e0[e];
        else if (e < 88)  v = e1[e-48];
        else if (e < 136) v = e2[e-88];
        else if (e < 164) v = e3[e-136];
        else              v = e4[e-164];
        smF[A0_EMB + e] = v;
    }
    for (int f = w; f < 8; f += 4){
        uint4 fr;
        if (f < 4){ int n = f >> 1, ks = f & 1;
                    fr = load_bfrag(Wd1, 36, 16*n + c, 32*ks + 8*q, 36); }
        else      { int n = f - 4;
                    fr = load_bfrag(Wd2, 32, 16*n + c, 8*q, 32); }
        *reinterpret_cast<uint4*>(sm + A0_WM + (f*64 + l)*4) = fr;
    }
    for (int e = tid; e < 64*18; e += 256){
        int row = e / 18, j = 18 + e % 18;
        sm[A0_CAT + row*36 + j] = 0u;
    }
    const float bb10 = bd1[c],  bb11 = bd1[16+c];
    const float bb20 = bd2[c],  bb21 = bd2[16+c];
    const float bb22 = bd2[32+c], bb23 = bd2[48+c];
    __syncthreads();

    for (int tile = blockIdx.x; tile < NT_; tile += gridDim.x){
        const int gb = tile / 42, tb = tile % 42;
        for (int e = tid; e < 1024; e += 256)
            smF[A0_ATT + e] = attnI[(size_t)(16*gb)*64 + e];
        for (int e = tid; e < 64*18; e += 256){
            int row = e / 18, j = e % 18;
            int R = (16*gb + (row & 15))*S_ + 4*tb + (row >> 4);
            float c0, c1;
            if (j < 8){
                c0 = sf[(size_t)R*16 + 2*j]; c1 = sf[(size_t)R*16 + 2*j + 1];
            } else {
                int jj = j - 8, ebl = jj >> 1, d0 = (jj & 1) * 2;
                int idx = se[(size_t)R*5 + ebl] - (ebl >= 2 ? 1 : 0);
                const int toff = (ebl==0)?0:(ebl==1)?48:(ebl==2)?88:(ebl==3)?136:164;
                c0 = smF[A0_EMB + toff + idx*4 + d0];
                c1 = smF[A0_EMB + toff + idx*4 + d0 + 1];
            }
            sm[A0_CAT + row*36 + j] = pack_h2f(c0, c1);
        }
        __syncthreads();

        {
            f32x4 c1a[2];
            c1a[0] = (f32x4){bb10, bb10, bb10, bb10};
            c1a[1] = (f32x4){bb11, bb11, bb11, bb11};
            #pragma unroll
            for (int ks = 0; ks < 2; ++ks){
                uint4 a = *reinterpret_cast<const uint4*>(
                    sm + A0_CAT + (16*w + c)*36 + ks*16 + 4*q);
                #pragma unroll
                for (int n = 0; n < 2; ++n)
                    c1a[n] = mfma16(a, *reinterpret_cast<const uint4*>(
                        sm + A0_WM + ((n*2 + ks)*64 + l)*4), c1a[n]);
            }
            #pragma unroll
            for (int n = 0; n < 2; ++n)
                #pragma unroll
                for (int j = 0; j < 4; ++j){
                    float v = fast_tanh(c1a[n][j]);
                    float vp = __shfl_xor(v, 1);
                    if (!(l & 1))
                        sm[A0_H1 + (16*w + 4*q + j)*20 + 8*n + (c >> 1)] = pack_h2f(v, vp);
                }
        }
        wsync();

        {
            uint4 a = *reinterpret_cast<const uint4*>(
                sm + A0_H1 + (16*w + c)*20 + 4*q);
            f32x4 c2[4];
            c2[0] = (f32x4){bb20, bb20, bb20, bb20};
            c2[1] = (f32x4){bb21, bb21, bb21, bb21};
            c2[2] = (f32x4){bb22, bb22, bb22, bb22};
            c2[3] = (f32x4){bb23, bb23, bb23, bb23};
            #pragma unroll
            for (int n = 0; n < 4; ++n)
                c2[n] = mfma16(a, *reinterpret_cast<const uint4*>(
                    sm + A0_WM + ((4 + n)*64 + l)*4), c2[n]);
            #pragma unroll
            for (int n = 0; n < 4; ++n)
                #pragma unroll
                for (int j = 0; j < 4; ++j){
                    float s  = fast_tanh(c2[n][j]);
                    float fa = smF[A0_ATT + (4*q + j)*64 + 16*n + c] * s;
                    float sp  = __shfl_xor(s, 1);
                    float fap = __shfl_xor(fa, 1);
                    if (!(l & 1)){
                        int row = 16*w + 4*q + j;
                        int ci = 8*n + (c >> 1);
                        sm[A0_FT + row*68 + ci]      = pack_h2f(fa, fap);
                        sm[A0_FT + row*68 + 32 + ci] = pack_h2f(s, sp);
                    }
                }
        }
        wsync();

        {
            const int t = 4*tb + w;
            size_t base = ((size_t)(gb*S_ + t))*1024;
            #pragma unroll
            for (int ks = 0; ks < 4; ++ks){
                uint4 af = *reinterpret_cast<const uint4*>(
                    sm + A0_FT + (16*w + c)*68 + ks*16 + 4*q);
                *reinterpret_cast<uint4*>(featF + base + ks*256 + l*4) = af;
            }
        }
        __syncthreads();
    }
}

// ---------- kernel 3: FUSED GRU layer0 + layer1 + pred (MFMA recurrence) ----------
// block = 16 batch rows, wave w owns h-cols 16w..16w+15 for BOTH layers.
// iteration i: L0 computes h0(i) (i<S_); L1 computes h1(i-1) (i>=1).
// h exchange: double-buffered swizzled LDS tiles, ONE raw barrier per iteration.
#define W0SZ 19200            // [192][100] u32
#define W1SZ 13056            // [192][68] u32
#define HB0  (W0SZ + W1SZ)    // 4 x 512 u32: h0 buf0, h0 buf1, h1 buf0, h1 buf1
#define RF_TOT (HB0 + 2048)

__global__ __launch_bounds__(256, 1)
void nbst_recf(const u32* __restrict__ featF,
               const float* __restrict__ Wih0, const float* __restrict__ Whh0,
               const float* __restrict__ bih0, const float* __restrict__ bhh0,
               const float* __restrict__ Wih1, const float* __restrict__ Whh1,
               const float* __restrict__ bih1, const float* __restrict__ bhh1,
               const float* __restrict__ Wpred, const float* __restrict__ bpred,
               float* __restrict__ outp)
{
    extern __shared__ u32 sm[];
    u32* smw0 = sm;
    u32* smw1 = sm + W0SZ;
    u32* HB   = sm + HB0;
    const int tid = threadIdx.x, w = tid >> 6, l = tid & 63;
    const int q = l >> 4, c = l & 15;
    const int g = blockIdx.x, B0 = g*16;

    for (int e = tid; e < 192*96; e += 256){
        int row = e / 96, kp = e % 96;
        smw0[row*100 + kp] = (kp < 64)
            ? pack_h2f(Wih0[row*128 + 2*kp],     Wih0[row*128 + 2*kp + 1])
            : pack_h2f(Whh0[row*64 + 2*(kp-64)], Whh0[row*64 + 2*(kp-64) + 1]);
    }
    for (int e = tid; e < 192*64; e += 256){
        int row = e / 64, kp = e % 64;
        smw1[row*68 + kp] = (kp < 32)
            ? pack_h2f(Wih1[row*64 + 2*kp],      Wih1[row*64 + 2*kp + 1])
            : pack_h2f(Whh1[row*64 + 2*(kp-32)], Whh1[row*64 + 2*(kp-32) + 1]);
    }
    for (int e = tid; e < 2048; e += 256) HB[e] = 0u;
    __syncthreads();

    const int gr = 16*w + c, gz = 64 + 16*w + c, gn = 128 + 16*w + c;
    // L0 B-frags: K = [feat 0..127 | h0 128..191]
    uint4 aBR[6], aBZ[6], aBXN[4], aBHN[2];
    #pragma unroll
    for (int ks = 0; ks < 6; ++ks){
        aBR[ks] = *reinterpret_cast<const uint4*>(smw0 + gr*100 + 16*ks + 4*q);
        aBZ[ks] = *reinterpret_cast<const uint4*>(smw0 + gz*100 + 16*ks + 4*q);
    }
    #pragma unroll
    for (int ks = 0; ks < 4; ++ks)
        aBXN[ks] = *reinterpret_cast<const uint4*>(smw0 + gn*100 + 16*ks + 4*q);
    aBHN[0] = *reinterpret_cast<const uint4*>(smw0 + gn*100 + 64 + 4*q);
    aBHN[1] = *reinterpret_cast<const uint4*>(smw0 + gn*100 + 80 + 4*q);
    // L1 B-frags: K = [o0 0..63 | h1 64..127]
    uint4 xBR[2], xBZ[2], xBXN[2], hBR[2], hBZ[2], hBHN[2];
    #pragma unroll
    for (int ks = 0; ks < 2; ++ks){
        xBR[ks] = *reinterpret_cast<const uint4*>(smw1 + gr*68 + 16*ks + 4*q);
        xBZ[ks] = *reinterpret_cast<const uint4*>(smw1 + gz*68 + 16*ks + 4*q);
        hBR[ks] = *reinterpret_cast<const uint4*>(smw1 + gr*68 + 32 + 16*ks + 4*q);
        hBZ[ks] = *reinterpret_cast<const uint4*>(smw1 + gz*68 + 32 + 16*ks + 4*q);
    }
    xBXN[0] = *reinterpret_cast<const uint4*>(smw1 + gn*68 +      4*q);
    xBXN[1] = *reinterpret_cast<const uint4*>(smw1 + gn*68 + 16 + 4*q);
    hBHN[0] = *reinterpret_cast<const uint4*>(smw1 + gn*68 + 32 + 4*q);
    hBHN[1] = *reinterpret_cast<const uint4*>(smw1 + gn*68 + 48 + 4*q);

    const float br0 = bih0[gr] + bhh0[gr], bz0 = bih0[gz] + bhh0[gz];
    const float bxn0 = bih0[gn], bhn0 = bhh0[gn];
    const float br1 = bih1[gr] + bhh1[gr], bz1 = bih1[gz] + bhh1[gz];
    const float bxn1 = bih1[gn], bhn1 = bhh1[gn];

    // swizzled A-frag reads (row=c): u32 idx XOR (c&7)<<2
    const int rd0 = (c*32 + 4*q)      ^ ((c & 7) << 2);
    const int rd1 = (c*32 + 4*q + 16) ^ ((c & 7) << 2);
    // swizzled u16 writes: idx16 = (row*64 + col) ^ ((row&7)<<3)
    int wri[4];
    #pragma unroll
    for (int j = 0; j < 4; ++j){
        int row = 4*q + j;
        wri[j] = (row*64 + 16*w + c) ^ ((row & 7) << 3);
    }

    const u32* fbase = featF + (size_t)g * S_ * 1024;
    uint4 fA0, fA1, fA2, fA3, fB0, fB1, fB2, fB3;
    fA0 = *reinterpret_cast<const uint4*>(fbase + 0*256 + l*4);
    fA1 = *reinterpret_cast<const uint4*>(fbase + 1*256 + l*4);
    fA2 = *reinterpret_cast<const uint4*>(fbase + 2*256 + l*4);
    fA3 = *reinterpret_cast<const uint4*>(fbase + 3*256 + l*4);
    fB0 = *reinterpret_cast<const uint4*>(fbase + 1024 + 0*256 + l*4);
    fB1 = *reinterpret_cast<const uint4*>(fbase + 1024 + 1*256 + l*4);
    fB2 = *reinterpret_cast<const uint4*>(fbase + 1024 + 2*256 + l*4);
    fB3 = *reinterpret_cast<const uint4*>(fbase + 1024 + 3*256 + l*4);
    float h0r0 = 0.f, h0r1 = 0.f, h0r2 = 0.f, h0r3 = 0.f;
    float h1r0 = 0.f, h1r1 = 0.f, h1r2 = 0.f, h1r3 = 0.f;
    __syncthreads();

    #pragma unroll 1
    for (int i = 0; i <= S_; ++i){
        // 2-step-ahead prefetch (stays in flight across the raw barrier)
        uint4 fC0, fC1, fC2, fC3;
        {
            int tn = (i + 2 < S_) ? i + 2 : S_ - 1;
            const u32* fp = fbase + (size_t)tn * 1024;
            fC0 = *reinterpret_cast<const uint4*>(fp + 0*256 + l*4);
            fC1 = *reinterpret_cast<const uint4*>(fp + 1*256 + l*4);
            fC2 = *reinterpret_cast<const uint4*>(fp + 2*256 + l*4);
            fC3 = *reinterpret_cast<const uint4*>(fp + 3*256 + l*4);
        }
        const u32* hp0 = HB + ((i + 1) & 1) * 512;          // h0(i-1)
        const u32* hp1 = HB + 1024 + ((i + 1) & 1) * 512;   // h1(i-2)
        uint4 hA0a = *reinterpret_cast<const uint4*>(hp0 + rd0);
        uint4 hA0b = *reinterpret_cast<const uint4*>(hp0 + rd1);
        uint4 hA1a = *reinterpret_cast<const uint4*>(hp1 + rd0);
        uint4 hA1b = *reinterpret_cast<const uint4*>(hp1 + rd1);

        if (i < S_){   // ---- layer 0: h0(i) ----
            f32x4 aRf = {0,0,0,0}, aZf = {0,0,0,0}, aXNf = {0,0,0,0};
            aRf  = mfma16(fA0, aBR[0], aRf);  aRf  = mfma16(fA1, aBR[1], aRf);
            aRf  = mfma16(fA2, aBR[2], aRf);  aRf  = mfma16(fA3, aBR[3], aRf);
            aZf  = mfma16(fA0, aBZ[0], aZf);  aZf  = mfma16(fA1, aBZ[1], aZf);
            aZf  = mfma16(fA2, aBZ[2], aZf);  aZf  = mfma16(fA3, aBZ[3], aZf);
            aXNf = mfma16(fA0, aBXN[0], aXNf); aXNf = mfma16(fA1, aBXN[1], aXNf);
            aXNf = mfma16(fA2, aBXN[2], aXNf); aXNf = mfma16(fA3, aBXN[3], aXNf);
            f32x4 aRh = {0,0,0,0}, aZh = {0,0,0,0}, aHN = {0,0,0,0};
            aRh = mfma16(hA0a, aBR[4], aRh);  aRh = mfma16(hA0b, aBR[5], aRh);
            aZh = mfma16(hA0a, aBZ[4], aZh);  aZh = mfma16(hA0b, aBZ[5], aZh);
            aHN = mfma16(hA0a, aBHN[0], aHN); aHN = mfma16(hA0b, aBHN[1], aHN);
            _Float16* hw = (_Float16*)(HB + (i & 1) * 512);
            float rg, zg, ng;
            rg = fast_sigmoid(aRf[0] + aRh[0] + br0); zg = fast_sigmoid(aZf[0] + aZh[0] + bz0);
            ng = fast_tanh(aXNf[0] + bxn0 + rg*(aHN[0] + bhn0));
            h0r0 = (1.f - zg)*ng + zg*h0r0; hw[wri[0]] = (_Float16)h0r0;
            rg = fast_sigmoid(aRf[1] + aRh[1] + br0); zg = fast_sigmoid(aZf[1] + aZh[1] + bz0);
            ng = fast_tanh(aXNf[1] + bxn0 + rg*(aHN[1] + bhn0));
            h0r1 = (1.f - zg)*ng + zg*h0r1; hw[wri[1]] = (_Float16)h0r1;
            rg = fast_sigmoid(aRf[2] + aRh[2] + br0); zg = fast_sigmoid(aZf[2] + aZh[2] + bz0);
            ng = fast_tanh(aXNf[2] + bxn0 + rg*(aHN[2] + bhn0));
            h0r2 = (1.f - zg)*ng + zg*h0r2; hw[wri[2]] = (_Float16)h0r2;
            rg = fast_sigmoid(aRf[3] + aRh[3] + br0); zg = fast_sigmoid(aZf[3] + aZh[3] + bz0);
            ng = fast_tanh(aXNf[3] + bxn0 + rg*(aHN[3] + bhn0));
            h0r3 = (1.f - zg)*ng + zg*h0r3; hw[wri[3]] = (_Float16)h0r3;
        }
        if (i >= 1){   // ---- layer 1: h1(i-1), x = o0(i-1) = hA0 ----
            f32x4 cR = {0,0,0,0}, cZ = {0,0,0,0}, cXN = {0,0,0,0}, cHN = {0,0,0,0};
            cR  = mfma16(hA0a, xBR[0], cR);   cR  = mfma16(hA0b, xBR[1], cR);
            cZ  = mfma16(hA0a, xBZ[0], cZ);   cZ  = mfma16(hA0b, xBZ[1], cZ);
            cXN = mfma16(hA0a, xBXN[0], cXN); cXN = mfma16(hA0b, xBXN[1], cXN);
            cR  = mfma16(hA1a, hBR[0], cR);   cR  = mfma16(hA1b, hBR[1], cR);
            cZ  = mfma16(hA1a, hBZ[0], cZ);   cZ  = mfma16(hA1b, hBZ[1], cZ);
            cHN = mfma16(hA1a, hBHN[0], cHN); cHN = mfma16(hA1b, hBHN[1], cHN);
            _Float16* hw = (_Float16*)(HB + 1024 + (i & 1) * 512);
            float rg, zg, ng;
            rg = fast_sigmoid(cR[0] + br1); zg = fast_sigmoid(cZ[0] + bz1);
            ng = fast_tanh(cXN[0] + bxn1 + rg*(cHN[0] + bhn1));
            h1r0 = (1.f - zg)*ng + zg*h1r0; hw[wri[0]] = (_Float16)h1r0;
            rg = fast_sigmoid(cR[1] + br1); zg = fast_sigmoid(cZ[1] + bz1);
            ng = fast_tanh(cXN[1] + bxn1 + rg*(cHN[1] + bhn1));
            h1r1 = (1.f - zg)*ng + zg*h1r1; hw[wri[1]] = (_Float16)h1r1;
            rg = fast_sigmoid(cR[2] + br1); zg = fast_sigmoid(cZ[2] + bz1);
            ng = fast_tanh(cXN[2] + bxn1 + rg*(cHN[2] + bhn1));
            h1r2 = (1.f - zg)*ng + zg*h1r2; hw[wri[2]] = (_Float16)h1r2;
            rg = fast_sigmoid(cR[3] + br1); zg = fast_sigmoid(cZ[3] + bz1);
            ng = fast_tanh(cXN[3] + bxn1 + rg*(cHN[3] + bhn1));
            h1r3 = (1.f - zg)*ng + zg*h1r3; hw[wri[3]] = (_Float16)h1r3;
        }
        bar_lds();   // single barrier per step; no vmcnt drain
        fA0 = fB0; fA1 = fB1; fA2 = fB2; fA3 = fB3;
        fB0 = fC0; fB1 = fC1; fB2 = fC2; fB3 = fC3;
    }

    // ---- pred head: f32 finals via LDS scratch (weights region is dead) ----
    float* s0 = reinterpret_cast<float*>(sm);
    float* s1 = reinterpret_cast<float*>(sm) + 1024;
    #pragma unroll
    for (int j = 0; j < 4; ++j){
        int row = 4*q + j;
        float h0v = (j == 0) ? h0r0 : (j == 1) ? h0r1 : (j == 2) ? h0r2 : h0r3;
        float h1v = (j == 0) ? h1r0 : (j == 1) ? h1r1 : (j == 2) ? h1r2 : h1r3;
        s0[row*64 + 16*w + c] = h0v;
        s1[row*64 + 16*w + c] = h1v;
    }
    __syncthreads();
    {
        const int r = tid >> 4, cg = tid & 15;
        const float* hp0 = s0 + r*64 + 4*cg;
        const float* hp1 = s1 + r*64 + 4*cg;
        const float* wp0 = Wpred + 4*cg;
        const float* wp1 = Wpred + 64 + 4*cg;
        float part = hp0[0]*wp0[0] + hp0[1]*wp0[1] + hp0[2]*wp0[2] + hp0[3]*wp0[3]
                   + hp1[0]*wp1[0] + hp1[1]*wp1[1] + hp1[2]*wp1[2] + hp1[3]*wp1[3];
        part += __shfl_xor(part, 8);
        part += __shfl_xor(part, 4);
        part += __shfl_xor(part, 2);
        part += __shfl_xor(part, 1);
        if (cg == 0) outp[B0 + r] = fast_tanh(part + bpred[0]);
    }
}

// ---------- launcher ----------
extern "C" void kernel_launch(void* const* d_in, const int* in_sizes, int n_in,
                              void* d_out, int out_size, void* d_ws, size_t ws_size,
                              hipStream_t stream) {
    (void)in_sizes; (void)n_in; (void)out_size; (void)ws_size;
    const float* station_nodes    = (const float*)d_in[1];
    const float* station_features = (const float*)d_in[2];
    const int*   station_emb      = (const int*)d_in[3];
    const float* e0 = (const float*)d_in[4];
    const float* e1 = (const float*)d_in[5];
    const float* e2 = (const float*)d_in[6];
    const float* e3 = (const float*)d_in[7];
    const float* e4 = (const float*)d_in[8];
    const float* W_nodes = (const float*)d_in[9];
    const float* b_nodes = (const float*)d_in[10];
    const float* W_attn  = (const float*)d_in[11];
    const float* W_d1 = (const float*)d_in[13];
    const float* b_d1 = (const float*)d_in[14];
    const float* W_d2 = (const float*)d_in[15];
    const float* b_d2 = (const float*)d_in[16];
    const float* Wih0 = (const float*)d_in[17];
    const float* Whh0 = (const float*)d_in[18];
    const float* bih0 = (const float*)d_in[19];
    const float* bhh0 = (const float*)d_in[20];
    const float* Wih1 = (const float*)d_in[21];
    const float* Whh1 = (const float*)d_in[22];
    const float* bih1 = (const float*)d_in[23];
    const float* bhh1 = (const float*)d_in[24];
    const float* W_pred = (const float*)d_in[25];
    const float* b_pred = (const float*)d_in[26];
    float* outp = (float*)d_out;

    char* ws = (char*)d_ws;
    float* attnW = (float*)ws;                 // 512 KiB
    u32*   featF = (u32*)(ws + (1u<<20));      // 128*168*1024 u32 = 88 MB

    hipFuncSetAttribute((const void*)nbst_recf,
                        hipFuncAttributeMaxDynamicSharedMemorySize, 144*1024);

    nbst_attn<<<dim3(512), dim3(256), 0, stream>>>(station_nodes, W_nodes, b_nodes, W_attn, attnW);
    nbst_mlpxg0<<<dim3(768), dim3(256), 0, stream>>>(
        station_features, station_emb, e0, e1, e2, e3, e4,
        W_d1, b_d1, W_d2, b_d2, attnW, featF);
    nbst_recf<<<dim3(128), dim3(256), RF_TOT*4, stream>>>(
        featF, Wih0, Whh0, bih0, bhh0, Wih1, Whh1, bih1, bhh1,
        W_pred, b_pred, outp);
}

// Round 11
// 261.121 us; speedup vs baseline: 1.4696x; 1.0365x over previous
//
#include <hip/hip_runtime.h>
#include <cstdint>
#include <cstddef>

#define B_ 2048
#define S_ 168
#define NT_ 5376   // 128 groups x 42 t-tiles

// ---------- helpers ----------
typedef _Float16 h2_t __attribute__((ext_vector_type(2)));
typedef _Float16 f16x8 __attribute__((ext_vector_type(8)));
typedef float f32x4 __attribute__((ext_vector_type(4)));
typedef unsigned int u32;

__device__ __forceinline__ unsigned pack_h2f(float a, float b){
    h2_t v; v.x = (_Float16)a; v.y = (_Float16)b;
    return __builtin_bit_cast(unsigned, v);
}
__device__ __forceinline__ float fast_exp(float x){
    return __builtin_amdgcn_exp2f(x * 1.44269504088896340736f);
}
__device__ __forceinline__ float fast_sigmoid(float x){
    return __builtin_amdgcn_rcpf(1.0f + fast_exp(-x));
}
__device__ __forceinline__ float fast_tanh(float x){
    return 1.0f - 2.0f * __builtin_amdgcn_rcpf(1.0f + fast_exp(2.0f * x));
}
__device__ __forceinline__ void wsync(){
    asm volatile("s_waitcnt lgkmcnt(0)" ::: "memory");
    __builtin_amdgcn_wave_barrier();
}
// block barrier: LDS ordered, global loads may stay in flight
__device__ __forceinline__ void bar_lds(){
    asm volatile("s_waitcnt lgkmcnt(0)\n\ts_barrier" ::: "memory");
}
__device__ __forceinline__ f32x4 mfma16(uint4 a, uint4 b, f32x4 c){
    return __builtin_amdgcn_mfma_f32_16x16x32_f16(
        __builtin_bit_cast(f16x8, a), __builtin_bit_cast(f16x8, b), c, 0, 0, 0);
}
__device__ __forceinline__ uint4 load_bfrag(const float* __restrict__ W, int ldk,
                                            int o, int kk0, int kmax){
    float w[8];
    #pragma unroll
    for (int e = 0; e < 8; ++e){
        int kk = kk0 + e;
        w[e] = (kk < kmax) ? W[o*ldk + kk] : 0.f;
    }
    uint4 r;
    r.x = pack_h2f(w[0], w[1]); r.y = pack_h2f(w[2], w[3]);
    r.z = pack_h2f(w[4], w[5]); r.w = pack_h2f(w[6], w[7]);
    return r;
}

// ---------- kernel 1: attention over stations (proven) ----------
__global__ void nbst_attn(const float* __restrict__ sn, const float* __restrict__ Wn,
                          const float* __restrict__ bn, const float* __restrict__ Wa,
                          float* __restrict__ attnO){
    __shared__ float WnL[64*16];
    __shared__ float WsL[64];
    __shared__ float bnL[64];
    const int tid = threadIdx.x;
    for (int e = tid; e < 1024; e += 256) WnL[e] = Wn[e];
    if (tid < 64){ WsL[tid] = Wa[64 + tid]; bnL[tid] = bn[tid]; }
    __syncthreads();
    const int wv = tid >> 6, l = tid & 63;
    const int b = blockIdx.x * 4 + wv;
    const float* xp = sn + ((size_t)b * 64 + l) * 16;
    float x[16];
    #pragma unroll
    for (int k = 0; k < 16; ++k) x[k] = xp[k];
    float e_i = 0.f;
    for (int h = 0; h < 64; ++h){
        float acc = bnL[h];
        #pragma unroll
        for (int k = 0; k < 16; ++k) acc += x[k] * WnL[h*16 + k];
        e_i += fast_tanh(acc) * WsL[h];
    }
    float m = e_i;
    #pragma unroll
    for (int s = 32; s >= 1; s >>= 1) m = fmaxf(m, __shfl_xor(m, s));
    float p = fast_exp(e_i - m);
    float ssum = p;
    #pragma unroll
    for (int s = 32; s >= 1; s >>= 1) ssum += __shfl_xor(ssum, s);
    attnO[(size_t)b*64 + l] = p * __builtin_amdgcn_rcpf(ssum);
}

// ---------- kernel 2: persistent MLP + xg0 GEMM -> gate C-frags ----------
// tile = (gb,tb): 16 batch x 4 times. m-tile m = time 4tb+m, M-rows = batch.
// P3 computes xg0 = feat @ Wih0^T and stores C-frags in recf's lane layout:
// xg0F[(g*S+t)*1536 + w*384 + k*64 + l], k = 2*nn+p (nn: 0=R,1=Z,2=XN).
#define A0_CAT 0      // [64][36] u32
#define A0_H1  2304   // [64][20]
#define A0_FT  3584   // [64][68]
#define A0_WM  7936   // [8 frags][64 lanes][4]
#define A0_EMB 9984   // 260 f32
#define A0_ATT 10244  // 1024 f32
#define A0_TOT 11268

__global__ __launch_bounds__(256, 2)
void nbst_mlpxg0(const float* __restrict__ sf, const int* __restrict__ se,
                 const float* __restrict__ e0, const float* __restrict__ e1,
                 const float* __restrict__ e2, const float* __restrict__ e3,
                 const float* __restrict__ e4,
                 const float* __restrict__ Wd1, const float* __restrict__ bd1,
                 const float* __restrict__ Wd2, const float* __restrict__ bd2,
                 const float* __restrict__ Wih0, const float* __restrict__ attnI,
                 u32* __restrict__ xg0F)
{
    __shared__ u32 sm[A0_TOT];
    float* smF = reinterpret_cast<float*>(sm);
    const int tid = threadIdx.x;
    const int w = tid >> 6, l = tid & 63;
    const int q = l >> 4, c = l & 15;

    for (int e = tid; e < 260; e += 256){
        float v;
        if (e < 48)       v = e0[e];
        else if (e < 88)  v = e1[e-48];
        else if (e < 136) v = e2[e-88];
        else if (e < 164) v = e3[e-136];
        else              v = e4[e-164];
        smF[A0_EMB + e] = v;
    }
    for (int f = w; f < 8; f += 4){
        uint4 fr;
        if (f < 4){ int n = f >> 1, ks = f & 1;
                    fr = load_bfrag(Wd1, 36, 16*n + c, 32*ks + 8*q, 36); }
        else      { int n = f - 4;
                    fr = load_bfrag(Wd2, 32, 16*n + c, 8*q, 32); }
        *reinterpret_cast<uint4*>(sm + A0_WM + (f*64 + l)*4) = fr;
    }
    // Wih0 B-frags: wave w covers gate tiles {w, 4+w, 8+w}, K=128 (4 ks)
    uint4 bw[3][4];
    #pragma unroll
    for (int nn = 0; nn < 3; ++nn)
        #pragma unroll
        for (int ks = 0; ks < 4; ++ks)
            bw[nn][ks] = load_bfrag(Wih0, 128, 16*(w + 4*nn) + c, 32*ks + 8*q, 128);
    for (int e = tid; e < 64*18; e += 256){
        int row = e / 18, j = 18 + e % 18;
        sm[A0_CAT + row*36 + j] = 0u;
    }
    const float bb10 = bd1[c],  bb11 = bd1[16+c];
    const float bb20 = bd2[c],  bb21 = bd2[16+c];
    const float bb22 = bd2[32+c], bb23 = bd2[48+c];
    __syncthreads();

    for (int tile = blockIdx.x; tile < NT_; tile += gridDim.x){
        const int gb = tile / 42, tb = tile % 42;
        for (int e = tid; e < 1024; e += 256)
            smF[A0_ATT + e] = attnI[(size_t)(16*gb)*64 + e];
        for (int e = tid; e < 64*18; e += 256){
            int row = e / 18, j = e % 18;
            int R = (16*gb + (row & 15))*S_ + 4*tb + (row >> 4);
            float c0, c1;
            if (j < 8){
                c0 = sf[(size_t)R*16 + 2*j]; c1 = sf[(size_t)R*16 + 2*j + 1];
            } else {
                int jj = j - 8, ebl = jj >> 1, d0 = (jj & 1) * 2;
                int idx = se[(size_t)R*5 + ebl] - (ebl >= 2 ? 1 : 0);
                const int toff = (ebl==0)?0:(ebl==1)?48:(ebl==2)?88:(ebl==3)?136:164;
                c0 = smF[A0_EMB + toff + idx*4 + d0];
                c1 = smF[A0_EMB + toff + idx*4 + d0 + 1];
            }
            sm[A0_CAT + row*36 + j] = pack_h2f(c0, c1);
        }
        __syncthreads();

        // P1: h1 = tanh(cat @ Wd1^T + bd1)
        {
            f32x4 c1a[2];
            c1a[0] = (f32x4){bb10, bb10, bb10, bb10};
            c1a[1] = (f32x4){bb11, bb11, bb11, bb11};
            #pragma unroll
            for (int ks = 0; ks < 2; ++ks){
                uint4 a = *reinterpret_cast<const uint4*>(
                    sm + A0_CAT + (16*w + c)*36 + ks*16 + 4*q);
                #pragma unroll
                for (int n = 0; n < 2; ++n)
                    c1a[n] = mfma16(a, *reinterpret_cast<const uint4*>(
                        sm + A0_WM + ((n*2 + ks)*64 + l)*4), c1a[n]);
            }
            #pragma unroll
            for (int n = 0; n < 2; ++n)
                #pragma unroll
                for (int j = 0; j < 4; ++j){
                    float v = fast_tanh(c1a[n][j]);
                    float vp = __shfl_xor(v, 1);
                    if (!(l & 1))
                        sm[A0_H1 + (16*w + 4*q + j)*20 + 8*n + (c >> 1)] = pack_h2f(v, vp);
                }
        }
        wsync();

        // P2: sfe = tanh(h1 @ Wd2^T + bd2); feat = [attn*sfe | sfe]
        {
            uint4 a = *reinterpret_cast<const uint4*>(
                sm + A0_H1 + (16*w + c)*20 + 4*q);
            f32x4 c2[4];
            c2[0] = (f32x4){bb20, bb20, bb20, bb20};
            c2[1] = (f32x4){bb21, bb21, bb21, bb21};
            c2[2] = (f32x4){bb22, bb22, bb22, bb22};
            c2[3] = (f32x4){bb23, bb23, bb23, bb23};
            #pragma unroll
            for (int n = 0; n < 4; ++n)
                c2[n] = mfma16(a, *reinterpret_cast<const uint4*>(
                    sm + A0_WM + ((4 + n)*64 + l)*4), c2[n]);
            #pragma unroll
            for (int n = 0; n < 4; ++n)
                #pragma unroll
                for (int j = 0; j < 4; ++j){
                    float s  = fast_tanh(c2[n][j]);
                    float fa = smF[A0_ATT + (4*q + j)*64 + 16*n + c] * s;
                    float sp  = __shfl_xor(s, 1);
                    float fap = __shfl_xor(fa, 1);
                    if (!(l & 1)){
                        int row = 16*w + 4*q + j;
                        int ci = 8*n + (c >> 1);
                        sm[A0_FT + row*68 + ci]      = pack_h2f(fa, fap);
                        sm[A0_FT + row*68 + 32 + ci] = pack_h2f(s, sp);
                    }
                }
        }
        __syncthreads();  // all waves read all FT rows in P3

        // P3: xg0 C-frags = feat @ Wih0^T, packed f16 stores in recf layout
        #pragma unroll
        for (int m = 0; m < 4; ++m){
            uint4 af[4];
            #pragma unroll
            for (int ks = 0; ks < 4; ++ks)
                af[ks] = *reinterpret_cast<const uint4*>(
                    sm + A0_FT + (16*m + c)*68 + ks*16 + 4*q);
            f32x4 acc[3];
            #pragma unroll
            for (int nn = 0; nn < 3; ++nn) acc[nn] = (f32x4){0.f, 0.f, 0.f, 0.f};
            #pragma unroll
            for (int ks = 0; ks < 4; ++ks)
                #pragma unroll
                for (int nn = 0; nn < 3; ++nn)
                    acc[nn] = mfma16(af[ks], bw[nn][ks], acc[nn]);
            size_t base = ((size_t)(gb*S_ + 4*tb + m))*1536 + (size_t)w*384;
            #pragma unroll
            for (int nn = 0; nn < 3; ++nn){
                xg0F[base + (2*nn)*64 + l]     = pack_h2f(acc[nn][0], acc[nn][1]);
                xg0F[base + (2*nn + 1)*64 + l] = pack_h2f(acc[nn][2], acc[nn][3]);
            }
        }
        __syncthreads();   // before next tile's CAT/ATT overwrite
    }
}

// ---------- kernel 3: FUSED GRU L0+L1+pred, xg0 precomputed ----------
// block = 16 batch rows; wave w owns h-cols 16w..16w+15 for both layers.
// iter i: L0 computes h0(i) (i<S_), L1 computes h1(i-1) (i>=1).
// In-loop global traffic: 6 dwords/lane/step (xg0 gate pre-activations).
#define RW0 6912               // Whh0 [192][36] u32
#define RW1 13056              // [Wih1|Whh1] [192][68] u32
#define RHB (RW0 + RW1)
#define RF_TOT (RHB + 2048)

__global__ __launch_bounds__(256, 1)
void nbst_recf(const u32* __restrict__ xg0F,
               const float* __restrict__ Whh0,
               const float* __restrict__ bih0, const float* __restrict__ bhh0,
               const float* __restrict__ Wih1, const float* __restrict__ Whh1,
               const float* __restrict__ bih1, const float* __restrict__ bhh1,
               const float* __restrict__ Wpred, const float* __restrict__ bpred,
               float* __restrict__ outp)
{
    extern __shared__ u32 sm[];
    u32* smw0 = sm;
    u32* smw1 = sm + RW0;
    u32* HB   = sm + RHB;
    const int tid = threadIdx.x, w = tid >> 6, l = tid & 63;
    const int q = l >> 4, c = l & 15;
    const int g = blockIdx.x, B0 = g*16;

    for (int e = tid; e < 192*32; e += 256){
        int row = e >> 5, k = e & 31;
        smw0[row*36 + k] = pack_h2f(Whh0[row*64 + 2*k], Whh0[row*64 + 2*k + 1]);
    }
    for (int e = tid; e < 192*64; e += 256){
        int row = e / 64, kp = e % 64;
        smw1[row*68 + kp] = (kp < 32)
            ? pack_h2f(Wih1[row*64 + 2*kp],      Wih1[row*64 + 2*kp + 1])
            : pack_h2f(Whh1[row*64 + 2*(kp-32)], Whh1[row*64 + 2*(kp-32) + 1]);
    }
    for (int e = tid; e < 2048; e += 256) HB[e] = 0u;
    __syncthreads();

    const int gr = 16*w + c, gz = 64 + 16*w + c, gn = 128 + 16*w + c;
    // L0 B-frags: h part only (Whh0, K=64 -> 2 ks)
    uint4 aBR[2], aBZ[2], aBHN[2];
    #pragma unroll
    for (int ks = 0; ks < 2; ++ks){
        aBR[ks]  = *reinterpret_cast<const uint4*>(smw0 + gr*36 + 16*ks + 4*q);
        aBZ[ks]  = *reinterpret_cast<const uint4*>(smw0 + gz*36 + 16*ks + 4*q);
        aBHN[ks] = *reinterpret_cast<const uint4*>(smw0 + gn*36 + 16*ks + 4*q);
    }
    // L1 B-frags: K = [o0 0..63 | h1 64..127]
    uint4 xBR[2], xBZ[2], xBXN[2], hBR[2], hBZ[2], hBHN[2];
    #pragma unroll
    for (int ks = 0; ks < 2; ++ks){
        xBR[ks] = *reinterpret_cast<const uint4*>(smw1 + gr*68 + 16*ks + 4*q);
        xBZ[ks] = *reinterpret_cast<const uint4*>(smw1 + gz*68 + 16*ks + 4*q);
        hBR[ks] = *reinterpret_cast<const uint4*>(smw1 + gr*68 + 32 + 16*ks + 4*q);
        hBZ[ks] = *reinterpret_cast<const uint4*>(smw1 + gz*68 + 32 + 16*ks + 4*q);
    }
    xBXN[0] = *reinterpret_cast<const uint4*>(smw1 + gn*68 +      4*q);
    xBXN[1] = *reinterpret_cast<const uint4*>(smw1 + gn*68 + 16 + 4*q);
    hBHN[0] = *reinterpret_cast<const uint4*>(smw1 + gn*68 + 32 + 4*q);
    hBHN[1] = *reinterpret_cast<const uint4*>(smw1 + gn*68 + 48 + 4*q);

    const float br0 = bih0[gr] + bhh0[gr], bz0 = bih0[gz] + bhh0[gz];
    const float bxn0 = bih0[gn], bhn0 = bhh0[gn];
    const float br1 = bih1[gr] + bhh1[gr], bz1 = bih1[gz] + bhh1[gz];
    const float bxn1 = bih1[gn], bhn1 = bhh1[gn];

    const int rd0 = (c*32 + 4*q)      ^ ((c & 7) << 2);
    const int rd1 = (c*32 + 4*q + 16) ^ ((c & 7) << 2);
    int wri[4];
    #pragma unroll
    for (int j = 0; j < 4; ++j){
        int row = 4*q + j;
        wri[j] = (row*64 + 16*w + c) ^ ((row & 7) << 3);
    }

    const u32* xbase = xg0F + (size_t)g * S_ * 1536 + (size_t)w * 384;
    u32 xc[6], xn_[6];
    #pragma unroll
    for (int k = 0; k < 6; ++k){
        xc[k]  = xbase[k*64 + l];
        xn_[k] = xbase[1536 + k*64 + l];
    }
    float h0r0 = 0.f, h0r1 = 0.f, h0r2 = 0.f, h0r3 = 0.f;
    float h1r0 = 0.f, h1r1 = 0.f, h1r2 = 0.f, h1r3 = 0.f;
    __syncthreads();

    #pragma unroll 1
    for (int i = 0; i <= S_; ++i){
        u32 xf[6];
        {   // prefetch xg0(i+2); issued early, consumed 2 iterations later
            int tn = (i + 2 < S_) ? i + 2 : S_ - 1;
            const u32* xp = xbase + (size_t)tn * 1536;
            #pragma unroll
            for (int k = 0; k < 6; ++k) xf[k] = xp[k*64 + l];
        }
        const u32* hp0 = HB + ((i + 1) & 1) * 512;          // h0(i-1)
        const u32* hp1 = HB + 1024 + ((i + 1) & 1) * 512;   // h1(i-2)
        uint4 hA0a = *reinterpret_cast<const uint4*>(hp0 + rd0);
        uint4 hA0b = *reinterpret_cast<const uint4*>(hp0 + rd1);
        uint4 hA1a = *reinterpret_cast<const uint4*>(hp1 + rd0);
        uint4 hA1b = *reinterpret_cast<const uint4*>(hp1 + rd1);

        if (i < S_){   // ---- layer 0: h0(i) ----
            f32x4 aRh = {0,0,0,0}, aZh = {0,0,0,0}, aHN = {0,0,0,0};
            aRh = mfma16(hA0a, aBR[0], aRh);  aRh = mfma16(hA0b, aBR[1], aRh);
            aZh = mfma16(hA0a, aBZ[0], aZh);  aZh = mfma16(hA0b, aBZ[1], aZh);
            aHN = mfma16(hA0a, aBHN[0], aHN); aHN = mfma16(hA0b, aBHN[1], aHN);
            h2_t xR01 = __builtin_bit_cast(h2_t, xc[0]);
            h2_t xR23 = __builtin_bit_cast(h2_t, xc[1]);
            h2_t xZ01 = __builtin_bit_cast(h2_t, xc[2]);
            h2_t xZ23 = __builtin_bit_cast(h2_t, xc[3]);
            h2_t xN01 = __builtin_bit_cast(h2_t, xc[4]);
            h2_t xN23 = __builtin_bit_cast(h2_t, xc[5]);
            _Float16* hw = (_Float16*)(HB + (i & 1) * 512);
            float rg, zg, ng;
            rg = fast_sigmoid((float)xR01.x + aRh[0] + br0);
            zg = fast_sigmoid((float)xZ01.x + aZh[0] + bz0);
            ng = fast_tanh((float)xN01.x + bxn0 + rg*(aHN[0] + bhn0));
            h0r0 = (1.f - zg)*ng + zg*h0r0; hw[wri[0]] = (_Float16)h0r0;
            rg = fast_sigmoid((float)xR01.y + aRh[1] + br0);
            zg = fast_sigmoid((float)xZ01.y + aZh[1] + bz0);
            ng = fast_tanh((float)xN01.y + bxn0 + rg*(aHN[1] + bhn0));
            h0r1 = (1.f - zg)*ng + zg*h0r1; hw[wri[1]] = (_Float16)h0r1;
            rg = fast_sigmoid((float)xR23.x + aRh[2] + br0);
            zg = fast_sigmoid((float)xZ23.x + aZh[2] + bz0);
            ng = fast_tanh((float)xN23.x + bxn0 + rg*(aHN[2] + bhn0));
            h0r2 = (1.f - zg)*ng + zg*h0r2; hw[wri[2]] = (_Float16)h0r2;
            rg = fast_sigmoid((float)xR23.y + aRh[3] + br0);
            zg = fast_sigmoid((float)xZ23.y + aZh[3] + bz0);
            ng = fast_tanh((float)xN23.y + bxn0 + rg*(aHN[3] + bhn0));
            h0r3 = (1.f - zg)*ng + zg*h0r3; hw[wri[3]] = (_Float16)h0r3;
        }
        if (i >= 1){   // ---- layer 1: h1(i-1), x = o0(i-1) = hA0 ----
            f32x4 cR = {0,0,0,0}, cZ = {0,0,0,0}, cXN = {0,0,0,0}, cHN = {0,0,0,0};
            cR  = mfma16(hA0a, xBR[0], cR);   cR  = mfma16(hA0b, xBR[1], cR);
            cZ  = mfma16(hA0a, xBZ[0], cZ);   cZ  = mfma16(hA0b, xBZ[1], cZ);
            cXN = mfma16(hA0a, xBXN[0], cXN); cXN = mfma16(hA0b, xBXN[1], cXN);
            cR  = mfma16(hA1a, hBR[0], cR);   cR  = mfma16(hA1b, hBR[1], cR);
            cZ  = mfma16(hA1a, hBZ[0], cZ);   cZ  = mfma16(hA1b, hBZ[1], cZ);
            cHN = mfma16(hA1a, hBHN[0], cHN); cHN = mfma16(hA1b, hBHN[1], cHN);
            _Float16* hw = (_Float16*)(HB + 1024 + (i & 1) * 512);
            float rg, zg, ng;
            rg = fast_sigmoid(cR[0] + br1); zg = fast_sigmoid(cZ[0] + bz1);
            ng = fast_tanh(cXN[0] + bxn1 + rg*(cHN[0] + bhn1));
            h1r0 = (1.f - zg)*ng + zg*h1r0; hw[wri[0]] = (_Float16)h1r0;
            rg = fast_sigmoid(cR[1] + br1); zg = fast_sigmoid(cZ[1] + bz1);
            ng = fast_tanh(cXN[1] + bxn1 + rg*(cHN[1] + bhn1));
            h1r1 = (1.f - zg)*ng + zg*h1r1; hw[wri[1]] = (_Float16)h1r1;
            rg = fast_sigmoid(cR[2] + br1); zg = fast_sigmoid(cZ[2] + bz1);
            ng = fast_tanh(cXN[2] + bxn1 + rg*(cHN[2] + bhn1));
            h1r2 = (1.f - zg)*ng + zg*h1r2; hw[wri[2]] = (_Float16)h1r2;
            rg = fast_sigmoid(cR[3] + br1); zg = fast_sigmoid(cZ[3] + bz1);
            ng = fast_tanh(cXN[3] + bxn1 + rg*(cHN[3] + bhn1));
            h1r3 = (1.f - zg)*ng + zg*h1r3; hw[wri[3]] = (_Float16)h1r3;
        }
        bar_lds();
        #pragma unroll
        for (int k = 0; k < 6; ++k){ xc[k] = xn_[k]; xn_[k] = xf[k]; }
    }

    // ---- pred head: f32 finals via LDS scratch (weights region dead) ----
    float* s0 = reinterpret_cast<float*>(sm);
    float* s1 = reinterpret_cast<float*>(sm) + 1024;
    #pragma unroll
    for (int j = 0; j < 4; ++j){
        int row = 4*q + j;
        float h0v = (j == 0) ? h0r0 : (j == 1) ? h0r1 : (j == 2) ? h0r2 : h0r3;
        float h1v = (j == 0) ? h1r0 : (j == 1) ? h1r1 : (j == 2) ? h1r2 : h1r3;
        s0[row*64 + 16*w + c] = h0v;
        s1[row*64 + 16*w + c] = h1v;
    }
    __syncthreads();
    {
        const int r = tid >> 4, cg = tid & 15;
        const float* hp0 = s0 + r*64 + 4*cg;
        const float* hp1 = s1 + r*64 + 4*cg;
        const float* wp0 = Wpred + 4*cg;
        const float* wp1 = Wpred + 64 + 4*cg;
        float part = hp0[0]*wp0[0] + hp0[1]*wp0[1] + hp0[2]*wp0[2] + hp0[3]*wp0[3]
                   + hp1[0]*wp1[0] + hp1[1]*wp1[1] + hp1[2]*wp1[2] + hp1[3]*wp1[3];
        part += __shfl_xor(part, 8);
        part += __shfl_xor(part, 4);
        part += __shfl_xor(part, 2);
        part += __shfl_xor(part, 1);
        if (cg == 0) outp[B0 + r] = fast_tanh(part + bpred[0]);
    }
}

// ---------- launcher ----------
extern "C" void kernel_launch(void* const* d_in, const int* in_sizes, int n_in,
                              void* d_out, int out_size, void* d_ws, size_t ws_size,
                              hipStream_t stream) {
    (void)in_sizes; (void)n_in; (void)out_size; (void)ws_size;
    const float* station_nodes    = (const float*)d_in[1];
    const float* station_features = (const float*)d_in[2];
    const int*   station_emb      = (const int*)d_in[3];
    const float* e0 = (const float*)d_in[4];
    const float* e1 = (const float*)d_in[5];
    const float* e2 = (const float*)d_in[6];
    const float* e3 = (const float*)d_in[7];
    const float* e4 = (const float*)d_in[8];
    const float* W_nodes = (const float*)d_in[9];
    const float* b_nodes = (const float*)d_in[10];
    const float* W_attn  = (const float*)d_in[11];
    const float* W_d1 = (const float*)d_in[13];
    const float* b_d1 = (const float*)d_in[14];
    const float* W_d2 = (const float*)d_in[15];
    const float* b_d2 = (const float*)d_in[16];
    const float* Wih0 = (const float*)d_in[17];
    const float* Whh0 = (const float*)d_in[18];
    const float* bih0 = (const float*)d_in[19];
    const float* bhh0 = (const float*)d_in[20];
    const float* Wih1 = (const float*)d_in[21];
    const float* Whh1 = (const float*)d_in[22];
    const float* bih1 = (const float*)d_in[23];
    const float* bhh1 = (const float*)d_in[24];
    const float* W_pred = (const float*)d_in[25];
    const float* b_pred = (const float*)d_in[26];
    float* outp = (float*)d_out;

    char* ws = (char*)d_ws;
    float* attnW = (float*)ws;                 // 512 KiB
    u32*   xg0F  = (u32*)(ws + (1u<<20));      // 128*168*1536 u32 = 132 MB

    hipFuncSetAttribute((const void*)nbst_recf,
                        hipFuncAttributeMaxDynamicSharedMemorySize, 96*1024);

    nbst_attn<<<dim3(512), dim3(256), 0, stream>>>(station_nodes, W_nodes, b_nodes, W_attn, attnW);
    nbst_mlpxg0<<<dim3(768), dim3(256), 0, stream>>>(
        station_features, station_emb, e0, e1, e2, e3, e4,
        W_d1, b_d1, W_d2, b_d2, Wih0, attnW, xg0F);
    nbst_recf<<<dim3(128), dim3(256), RF_TOT*4, stream>>>(
        xg0F, Whh0, bih0, bhh0, Wih1, Whh1, bih1, bhh1,
        W_pred, b_pred, outp);
}

// Round 12
// 226.185 us; speedup vs baseline: 1.6966x; 1.1545x over previous
//
#include <hip/hip_runtime.h>
#include <cstdint>
#include <cstddef>

#define B_ 2048
#define S_ 168
#define NT_ 5376   // 128 groups x 42 t-tiles

// ---------- helpers ----------
typedef _Float16 h2_t __attribute__((ext_vector_type(2)));
typedef _Float16 f16x8 __attribute__((ext_vector_type(8)));
typedef float f32x4 __attribute__((ext_vector_type(4)));
typedef unsigned int u32;

__device__ __forceinline__ unsigned pack_h2f(float a, float b){
    h2_t v; v.x = (_Float16)a; v.y = (_Float16)b;
    return __builtin_bit_cast(unsigned, v);
}
__device__ __forceinline__ float fast_exp(float x){
    return __builtin_amdgcn_exp2f(x * 1.44269504088896340736f);
}
__device__ __forceinline__ float fast_sigmoid(float x){
    return __builtin_amdgcn_rcpf(1.0f + fast_exp(-x));
}
__device__ __forceinline__ float fast_tanh(float x){
    return 1.0f - 2.0f * __builtin_amdgcn_rcpf(1.0f + fast_exp(2.0f * x));
}
__device__ __forceinline__ void wsync(){
    asm volatile("s_waitcnt lgkmcnt(0)" ::: "memory");
    __builtin_amdgcn_wave_barrier();
}
// block barrier: LDS ordered, global loads may stay in flight
__device__ __forceinline__ void bar_lds(){
    asm volatile("s_waitcnt lgkmcnt(0)\n\ts_barrier" ::: "memory");
}
__device__ __forceinline__ f32x4 mfma16(uint4 a, uint4 b, f32x4 c){
    return __builtin_amdgcn_mfma_f32_16x16x32_f16(
        __builtin_bit_cast(f16x8, a), __builtin_bit_cast(f16x8, b), c, 0, 0, 0);
}
__device__ __forceinline__ uint4 load_bfrag(const float* __restrict__ W, int ldk,
                                            int o, int kk0, int kmax){
    float w[8];
    #pragma unroll
    for (int e = 0; e < 8; ++e){
        int kk = kk0 + e;
        w[e] = (kk < kmax) ? W[o*ldk + kk] : 0.f;
    }
    uint4 r;
    r.x = pack_h2f(w[0], w[1]); r.y = pack_h2f(w[2], w[3]);
    r.z = pack_h2f(w[4], w[5]); r.w = pack_h2f(w[6], w[7]);
    return r;
}

// ---------- kernel 1: attention over stations (proven) ----------
__global__ void nbst_attn(const float* __restrict__ sn, const float* __restrict__ Wn,
                          const float* __restrict__ bn, const float* __restrict__ Wa,
                          float* __restrict__ attnO){
    __shared__ float WnL[64*16];
    __shared__ float WsL[64];
    __shared__ float bnL[64];
    const int tid = threadIdx.x;
    for (int e = tid; e < 1024; e += 256) WnL[e] = Wn[e];
    if (tid < 64){ WsL[tid] = Wa[64 + tid]; bnL[tid] = bn[tid]; }
    __syncthreads();
    const int wv = tid >> 6, l = tid & 63;
    const int b = blockIdx.x * 4 + wv;
    const float* xp = sn + ((size_t)b * 64 + l) * 16;
    float x[16];
    #pragma unroll
    for (int k = 0; k < 16; ++k) x[k] = xp[k];
    float e_i = 0.f;
    for (int h = 0; h < 64; ++h){
        float acc = bnL[h];
        #pragma unroll
        for (int k = 0; k < 16; ++k) acc += x[k] * WnL[h*16 + k];
        e_i += fast_tanh(acc) * WsL[h];
    }
    float m = e_i;
    #pragma unroll
    for (int s = 32; s >= 1; s >>= 1) m = fmaxf(m, __shfl_xor(m, s));
    float p = fast_exp(e_i - m);
    float ssum = p;
    #pragma unroll
    for (int s = 32; s >= 1; s >>= 1) ssum += __shfl_xor(ssum, s);
    attnO[(size_t)b*64 + l] = p * __builtin_amdgcn_rcpf(ssum);
}

// ---------- kernel 2: persistent MLP + xg0 GEMM -> gate C-frags ----------
// xg0F layout (lane-contiguous): (g*S+t)*1536 + w*384 + l*6 + k,
// k = R01,R23,Z01,Z23,N01,N23 of lane l's C-frag.
#define A0_CAT 0      // [64][36] u32
#define A0_H1  2304   // [64][20]
#define A0_FT  3584   // [64][68]
#define A0_WM  7936   // [8 frags][64 lanes][4]
#define A0_EMB 9984   // 260 f32
#define A0_ATT 10244  // 1024 f32
#define A0_TOT 11268

__global__ __launch_bounds__(256, 2)
void nbst_mlpxg0(const float* __restrict__ sf, const int* __restrict__ se,
                 const float* __restrict__ e0, const float* __restrict__ e1,
                 const float* __restrict__ e2, const float* __restrict__ e3,
                 const float* __restrict__ e4,
                 const float* __restrict__ Wd1, const float* __restrict__ bd1,
                 const float* __restrict__ Wd2, const float* __restrict__ bd2,
                 const float* __restrict__ Wih0, const float* __restrict__ attnI,
                 u32* __restrict__ xg0F)
{
    __shared__ u32 sm[A0_TOT];
    float* smF = reinterpret_cast<float*>(sm);
    const int tid = threadIdx.x;
    const int w = tid >> 6, l = tid & 63;
    const int q = l >> 4, c = l & 15;

    for (int e = tid; e < 260; e += 256){
        float v;
        if (e < 48)       v = e0[e];
        else if (e < 88)  v = e1[e-48];
        else if (e < 136) v = e2[e-88];
        else if (e < 164) v = e3[e-136];
        else              v = e4[e-164];
        smF[A0_EMB + e] = v;
    }
    for (int f = w; f < 8; f += 4){
        uint4 fr;
        if (f < 4){ int n = f >> 1, ks = f & 1;
                    fr = load_bfrag(Wd1, 36, 16*n + c, 32*ks + 8*q, 36); }
        else      { int n = f - 4;
                    fr = load_bfrag(Wd2, 32, 16*n + c, 8*q, 32); }
        *reinterpret_cast<uint4*>(sm + A0_WM + (f*64 + l)*4) = fr;
    }
    uint4 bw[3][4];
    #pragma unroll
    for (int nn = 0; nn < 3; ++nn)
        #pragma unroll
        for (int ks = 0; ks < 4; ++ks)
            bw[nn][ks] = load_bfrag(Wih0, 128, 16*(w + 4*nn) + c, 32*ks + 8*q, 128);
    for (int e = tid; e < 64*18; e += 256){
        int row = e / 18, j = 18 + e % 18;
        sm[A0_CAT + row*36 + j] = 0u;
    }
    const float bb10 = bd1[c],  bb11 = bd1[16+c];
    const float bb20 = bd2[c],  bb21 = bd2[16+c];
    const float bb22 = bd2[32+c], bb23 = bd2[48+c];
    __syncthreads();

    for (int tile = blockIdx.x; tile < NT_; tile += gridDim.x){
        const int gb = tile / 42, tb = tile % 42;
        for (int e = tid; e < 1024; e += 256)
            smF[A0_ATT + e] = attnI[(size_t)(16*gb)*64 + e];
        for (int e = tid; e < 64*18; e += 256){
            int row = e / 18, j = e % 18;
            int R = (16*gb + (row & 15))*S_ + 4*tb + (row >> 4);
            float c0, c1;
            if (j < 8){
                c0 = sf[(size_t)R*16 + 2*j]; c1 = sf[(size_t)R*16 + 2*j + 1];
            } else {
                int jj = j - 8, ebl = jj >> 1, d0 = (jj & 1) * 2;
                int idx = se[(size_t)R*5 + ebl] - (ebl >= 2 ? 1 : 0);
                const int toff = (ebl==0)?0:(ebl==1)?48:(ebl==2)?88:(ebl==3)?136:164;
                c0 = smF[A0_EMB + toff + idx*4 + d0];
                c1 = smF[A0_EMB + toff + idx*4 + d0 + 1];
            }
            sm[A0_CAT + row*36 + j] = pack_h2f(c0, c1);
        }
        __syncthreads();

        // P1: h1 = tanh(cat @ Wd1^T + bd1)
        {
            f32x4 c1a[2];
            c1a[0] = (f32x4){bb10, bb10, bb10, bb10};
            c1a[1] = (f32x4){bb11, bb11, bb11, bb11};
            #pragma unroll
            for (int ks = 0; ks < 2; ++ks){
                uint4 a = *reinterpret_cast<const uint4*>(
                    sm + A0_CAT + (16*w + c)*36 + ks*16 + 4*q);
                #pragma unroll
                for (int n = 0; n < 2; ++n)
                    c1a[n] = mfma16(a, *reinterpret_cast<const uint4*>(
                        sm + A0_WM + ((n*2 + ks)*64 + l)*4), c1a[n]);
            }
            #pragma unroll
            for (int n = 0; n < 2; ++n)
                #pragma unroll
                for (int j = 0; j < 4; ++j){
                    float v = fast_tanh(c1a[n][j]);
                    float vp = __shfl_xor(v, 1);
                    if (!(l & 1))
                        sm[A0_H1 + (16*w + 4*q + j)*20 + 8*n + (c >> 1)] = pack_h2f(v, vp);
                }
        }
        wsync();

        // P2: sfe = tanh(h1 @ Wd2^T + bd2); feat = [attn*sfe | sfe]
        {
            uint4 a = *reinterpret_cast<const uint4*>(
                sm + A0_H1 + (16*w + c)*20 + 4*q);
            f32x4 c2[4];
            c2[0] = (f32x4){bb20, bb20, bb20, bb20};
            c2[1] = (f32x4){bb21, bb21, bb21, bb21};
            c2[2] = (f32x4){bb22, bb22, bb22, bb22};
            c2[3] = (f32x4){bb23, bb23, bb23, bb23};
            #pragma unroll
            for (int n = 0; n < 4; ++n)
                c2[n] = mfma16(a, *reinterpret_cast<const uint4*>(
                    sm + A0_WM + ((4 + n)*64 + l)*4), c2[n]);
            #pragma unroll
            for (int n = 0; n < 4; ++n)
                #pragma unroll
                for (int j = 0; j < 4; ++j){
                    float s  = fast_tanh(c2[n][j]);
                    float fa = smF[A0_ATT + (4*q + j)*64 + 16*n + c] * s;
                    float sp  = __shfl_xor(s, 1);
                    float fap = __shfl_xor(fa, 1);
                    if (!(l & 1)){
                        int row = 16*w + 4*q + j;
                        int ci = 8*n + (c >> 1);
                        sm[A0_FT + row*68 + ci]      = pack_h2f(fa, fap);
                        sm[A0_FT + row*68 + 32 + ci] = pack_h2f(s, sp);
                    }
                }
        }
        __syncthreads();

        // P3: xg0 C-frags = feat @ Wih0^T, lane-contiguous packed stores
        #pragma unroll
        for (int m = 0; m < 4; ++m){
            uint4 af[4];
            #pragma unroll
            for (int ks = 0; ks < 4; ++ks)
                af[ks] = *reinterpret_cast<const uint4*>(
                    sm + A0_FT + (16*m + c)*68 + ks*16 + 4*q);
            f32x4 acc[3];
            #pragma unroll
            for (int nn = 0; nn < 3; ++nn) acc[nn] = (f32x4){0.f, 0.f, 0.f, 0.f};
            #pragma unroll
            for (int ks = 0; ks < 4; ++ks)
                #pragma unroll
                for (int nn = 0; nn < 3; ++nn)
                    acc[nn] = mfma16(af[ks], bw[nn][ks], acc[nn]);
            size_t base = ((size_t)(gb*S_ + 4*tb + m))*1536 + (size_t)w*384 + (size_t)l*6;
            uint2 s01, s23, s45;
            s01.x = pack_h2f(acc[0][0], acc[0][1]); s01.y = pack_h2f(acc[0][2], acc[0][3]);
            s23.x = pack_h2f(acc[1][0], acc[1][1]); s23.y = pack_h2f(acc[1][2], acc[1][3]);
            s45.x = pack_h2f(acc[2][0], acc[2][1]); s45.y = pack_h2f(acc[2][2], acc[2][3]);
            *reinterpret_cast<uint2*>(xg0F + base + 0) = s01;
            *reinterpret_cast<uint2*>(xg0F + base + 2) = s23;
            *reinterpret_cast<uint2*>(xg0F + base + 4) = s45;
        }
        __syncthreads();
    }
}

// ---------- kernel 3: FUSED GRU L0+L1+pred, 4-deep static prefetch ----------
#define RW0 6912               // Whh0 [192][36] u32
#define RW1 13056              // [Wih1|Whh1] [192][68] u32
#define RHB (RW0 + RW1)
#define RF_TOT (RHB + 2048)

__global__ __launch_bounds__(256, 1)
void nbst_recf(const u32* __restrict__ xg0F,
               const float* __restrict__ Whh0,
               const float* __restrict__ bih0, const float* __restrict__ bhh0,
               const float* __restrict__ Wih1, const float* __restrict__ Whh1,
               const float* __restrict__ bih1, const float* __restrict__ bhh1,
               const float* __restrict__ Wpred, const float* __restrict__ bpred,
               float* __restrict__ outp)
{
    extern __shared__ u32 sm[];
    u32* smw0 = sm;
    u32* smw1 = sm + RW0;
    u32* HB   = sm + RHB;
    const int tid = threadIdx.x, w = tid >> 6, l = tid & 63;
    const int q = l >> 4, c = l & 15;
    const int g = blockIdx.x, B0 = g*16;

    for (int e = tid; e < 192*32; e += 256){
        int row = e >> 5, k = e & 31;
        smw0[row*36 + k] = pack_h2f(Whh0[row*64 + 2*k], Whh0[row*64 + 2*k + 1]);
    }
    for (int e = tid; e < 192*64; e += 256){
        int row = e / 64, kp = e % 64;
        smw1[row*68 + kp] = (kp < 32)
            ? pack_h2f(Wih1[row*64 + 2*kp],      Wih1[row*64 + 2*kp + 1])
            : pack_h2f(Whh1[row*64 + 2*(kp-32)], Whh1[row*64 + 2*(kp-32) + 1]);
    }
    for (int e = tid; e < 2048; e += 256) HB[e] = 0u;
    __syncthreads();

    const int gr = 16*w + c, gz = 64 + 16*w + c, gn = 128 + 16*w + c;
    uint4 aBR[2], aBZ[2], aBHN[2];
    #pragma unroll
    for (int ks = 0; ks < 2; ++ks){
        aBR[ks]  = *reinterpret_cast<const uint4*>(smw0 + gr*36 + 16*ks + 4*q);
        aBZ[ks]  = *reinterpret_cast<const uint4*>(smw0 + gz*36 + 16*ks + 4*q);
        aBHN[ks] = *reinterpret_cast<const uint4*>(smw0 + gn*36 + 16*ks + 4*q);
    }
    uint4 xBR[2], xBZ[2], xBXN[2], hBR[2], hBZ[2], hBHN[2];
    #pragma unroll
    for (int ks = 0; ks < 2; ++ks){
        xBR[ks] = *reinterpret_cast<const uint4*>(smw1 + gr*68 + 16*ks + 4*q);
        xBZ[ks] = *reinterpret_cast<const uint4*>(smw1 + gz*68 + 16*ks + 4*q);
        hBR[ks] = *reinterpret_cast<const uint4*>(smw1 + gr*68 + 32 + 16*ks + 4*q);
        hBZ[ks] = *reinterpret_cast<const uint4*>(smw1 + gz*68 + 32 + 16*ks + 4*q);
    }
    xBXN[0] = *reinterpret_cast<const uint4*>(smw1 + gn*68 +      4*q);
    xBXN[1] = *reinterpret_cast<const uint4*>(smw1 + gn*68 + 16 + 4*q);
    hBHN[0] = *reinterpret_cast<const uint4*>(smw1 + gn*68 + 32 + 4*q);
    hBHN[1] = *reinterpret_cast<const uint4*>(smw1 + gn*68 + 48 + 4*q);

    const float br0 = bih0[gr] + bhh0[gr], bz0 = bih0[gz] + bhh0[gz];
    const float bxn0 = bih0[gn], bhn0 = bhh0[gn];
    const float br1 = bih1[gr] + bhh1[gr], bz1 = bih1[gz] + bhh1[gz];
    const float bxn1 = bih1[gn], bhn1 = bhh1[gn];

    const int rd0 = (c*32 + 4*q)      ^ ((c & 7) << 2);
    const int rd1 = (c*32 + 4*q + 16) ^ ((c & 7) << 2);
    int wri[4];
    #pragma unroll
    for (int j = 0; j < 4; ++j){
        int row = 4*q + j;
        wri[j] = (row*64 + 16*w + c) ^ ((row & 7) << 3);
    }

    const u32* xb = xg0F + (size_t)g * S_ * 1536 + (size_t)w * 384 + (size_t)l * 6;
    // 4-deep STATIC prefetch sets: no rotation copies -> loads stay in
    // flight 4 iterations (~2800 cyc >> HBM latency), never drained per-step.
    uint2 x0a, x0b, x0c, x1a, x1b, x1c, x2a, x2b, x2c, x3a, x3b, x3c;
    {
        const u32* p0 = xb;
        const u32* p1 = xb + 1536;
        const u32* p2 = xb + 2*1536;
        const u32* p3 = xb + 3*1536;
        x0a = *(const uint2*)(p0+0); x0b = *(const uint2*)(p0+2); x0c = *(const uint2*)(p0+4);
        x1a = *(const uint2*)(p1+0); x1b = *(const uint2*)(p1+2); x1c = *(const uint2*)(p1+4);
        x2a = *(const uint2*)(p2+0); x2b = *(const uint2*)(p2+2); x2c = *(const uint2*)(p2+4);
        x3a = *(const uint2*)(p3+0); x3b = *(const uint2*)(p3+2); x3c = *(const uint2*)(p3+4);
    }
    float h0r0 = 0.f, h0r1 = 0.f, h0r2 = 0.f, h0r3 = 0.f;
    float h1r0 = 0.f, h1r1 = 0.f, h1r2 = 0.f, h1r3 = 0.f;
    __syncthreads();

#define RSTEP(I, XA, XB, XC, DOL1) do{                                          \
    const int i_ = (I);                                                         \
    const u32* hp0_ = HB + ((i_ + 1) & 1) * 512;                                \
    const u32* hp1_ = HB + 1024 + ((i_ + 1) & 1) * 512;                         \
    uint4 hA0a_ = *(const uint4*)(hp0_ + rd0);                                  \
    uint4 hA0b_ = *(const uint4*)(hp0_ + rd1);                                  \
    uint4 hA1a_ = *(const uint4*)(hp1_ + rd0);                                  \
    uint4 hA1b_ = *(const uint4*)(hp1_ + rd1);                                  \
    {   /* layer 0: h0(i) */                                                    \
        f32x4 aRh_ = {0,0,0,0}, aZh_ = {0,0,0,0}, aHN_ = {0,0,0,0};             \
        aRh_ = mfma16(hA0a_, aBR[0], aRh_);  aRh_ = mfma16(hA0b_, aBR[1], aRh_);\
        aZh_ = mfma16(hA0a_, aBZ[0], aZh_);  aZh_ = mfma16(hA0b_, aBZ[1], aZh_);\
        aHN_ = mfma16(hA0a_, aBHN[0], aHN_); aHN_ = mfma16(hA0b_, aBHN[1], aHN_);\
        h2_t xR01_ = __builtin_bit_cast(h2_t, (XA).x);                          \
        h2_t xR23_ = __builtin_bit_cast(h2_t, (XA).y);                          \
        h2_t xZ01_ = __builtin_bit_cast(h2_t, (XB).x);                          \
        h2_t xZ23_ = __builtin_bit_cast(h2_t, (XB).y);                          \
        h2_t xN01_ = __builtin_bit_cast(h2_t, (XC).x);                          \
        h2_t xN23_ = __builtin_bit_cast(h2_t, (XC).y);                          \
        _Float16* hw_ = (_Float16*)(HB + (i_ & 1) * 512);                       \
        float rg_, zg_, ng_;                                                    \
        rg_ = fast_sigmoid((float)xR01_.x + aRh_[0] + br0);                     \
        zg_ = fast_sigmoid((float)xZ01_.x + aZh_[0] + bz0);                     \
        ng_ = fast_tanh((float)xN01_.x + bxn0 + rg_*(aHN_[0] + bhn0));          \
        h0r0 = (1.f - zg_)*ng_ + zg_*h0r0; hw_[wri[0]] = (_Float16)h0r0;        \
        rg_ = fast_sigmoid((float)xR01_.y + aRh_[1] + br0);                     \
        zg_ = fast_sigmoid((float)xZ01_.y + aZh_[1] + bz0);                     \
        ng_ = fast_tanh((float)xN01_.y + bxn0 + rg_*(aHN_[1] + bhn0));          \
        h0r1 = (1.f - zg_)*ng_ + zg_*h0r1; hw_[wri[1]] = (_Float16)h0r1;        \
        rg_ = fast_sigmoid((float)xR23_.x + aRh_[2] + br0);                     \
        zg_ = fast_sigmoid((float)xZ23_.x + aZh_[2] + bz0);                     \
        ng_ = fast_tanh((float)xN23_.x + bxn0 + rg_*(aHN_[2] + bhn0));          \
        h0r2 = (1.f - zg_)*ng_ + zg_*h0r2; hw_[wri[2]] = (_Float16)h0r2;        \
        rg_ = fast_sigmoid((float)xR23_.y + aRh_[3] + br0);                     \
        zg_ = fast_sigmoid((float)xZ23_.y + aZh_[3] + bz0);                     \
        ng_ = fast_tanh((float)xN23_.y + bxn0 + rg_*(aHN_[3] + bhn0));          \
        h0r3 = (1.f - zg_)*ng_ + zg_*h0r3; hw_[wri[3]] = (_Float16)h0r3;        \
    }                                                                           \
    if (DOL1){  /* layer 1: h1(i-1), x = o0(i-1) = hA0 */                       \
        f32x4 cR_ = {0,0,0,0}, cZ_ = {0,0,0,0}, cXN_ = {0,0,0,0}, cHN_ = {0,0,0,0};\
        cR_  = mfma16(hA0a_, xBR[0], cR_);   cR_  = mfma16(hA0b_, xBR[1], cR_); \
        cZ_  = mfma16(hA0a_, xBZ[0], cZ_);   cZ_  = mfma16(hA0b_, xBZ[1], cZ_); \
        cXN_ = mfma16(hA0a_, xBXN[0], cXN_); cXN_ = mfma16(hA0b_, xBXN[1], cXN_);\
        cR_  = mfma16(hA1a_, hBR[0], cR_);   cR_  = mfma16(hA1b_, hBR[1], cR_); \
        cZ_  = mfma16(hA1a_, hBZ[0], cZ_);   cZ_  = mfma16(hA1b_, hBZ[1], cZ_); \
        cHN_ = mfma16(hA1a_, hBHN[0], cHN_); cHN_ = mfma16(hA1b_, hBHN[1], cHN_);\
        _Float16* hw_ = (_Float16*)(HB + 1024 + (i_ & 1) * 512);                \
        float rg_, zg_, ng_;                                                    \
        rg_ = fast_sigmoid(cR_[0] + br1); zg_ = fast_sigmoid(cZ_[0] + bz1);     \
        ng_ = fast_tanh(cXN_[0] + bxn1 + rg_*(cHN_[0] + bhn1));                 \
        h1r0 = (1.f - zg_)*ng_ + zg_*h1r0; hw_[wri[0]] = (_Float16)h1r0;        \
        rg_ = fast_sigmoid(cR_[1] + br1); zg_ = fast_sigmoid(cZ_[1] + bz1);     \
        ng_ = fast_tanh(cXN_[1] + bxn1 + rg_*(cHN_[1] + bhn1));                 \
        h1r1 = (1.f - zg_)*ng_ + zg_*h1r1; hw_[wri[1]] = (_Float16)h1r1;        \
        rg_ = fast_sigmoid(cR_[2] + br1); zg_ = fast_sigmoid(cZ_[2] + bz1);     \
        ng_ = fast_tanh(cXN_[2] + bxn1 + rg_*(cHN_[2] + bhn1));                 \
        h1r2 = (1.f - zg_)*ng_ + zg_*h1r2; hw_[wri[2]] = (_Float16)h1r2;        \
        rg_ = fast_sigmoid(cR_[3] + br1); zg_ = fast_sigmoid(cZ_[3] + bz1);     \
        ng_ = fast_tanh(cXN_[3] + bxn1 + rg_*(cHN_[3] + bhn1));                 \
        h1r3 = (1.f - zg_)*ng_ + zg_*h1r3; hw_[wri[3]] = (_Float16)h1r3;        \
    }                                                                           \
    {   /* reload this set for i+4 (consumed 4 iters later; no copies) */       \
        int tn_ = (i_ + 4 < S_) ? i_ + 4 : S_ - 1;                              \
        const u32* xp_ = xb + (size_t)tn_ * 1536;                               \
        (XA) = *(const uint2*)(xp_ + 0);                                        \
        (XB) = *(const uint2*)(xp_ + 2);                                        \
        (XC) = *(const uint2*)(xp_ + 4);                                        \
    }                                                                           \
    bar_lds();                                                                  \
} while(0)

    // peel first quad (i=0 has no L1)
    RSTEP(0, x0a, x0b, x0c, 0);
    RSTEP(1, x1a, x1b, x1c, 1);
    RSTEP(2, x2a, x2b, x2c, 1);
    RSTEP(3, x3a, x3b, x3c, 1);
    #pragma unroll 1
    for (int i4 = 1; i4 < 42; ++i4){
        const int ib = 4*i4;
        RSTEP(ib + 0, x0a, x0b, x0c, 1);
        RSTEP(ib + 1, x1a, x1b, x1c, 1);
        RSTEP(ib + 2, x2a, x2b, x2c, 1);
        RSTEP(ib + 3, x3a, x3b, x3c, 1);
    }
    {   // epilogue i = S_: layer 1 computes h1(167)
        const u32* hp0_ = HB + 512;           // h0(167), written at i=167 (odd)
        const u32* hp1_ = HB + 1024 + 512;    // h1(166)
        uint4 hA0a_ = *(const uint4*)(hp0_ + rd0);
        uint4 hA0b_ = *(const uint4*)(hp0_ + rd1);
        uint4 hA1a_ = *(const uint4*)(hp1_ + rd0);
        uint4 hA1b_ = *(const uint4*)(hp1_ + rd1);
        f32x4 cR_ = {0,0,0,0}, cZ_ = {0,0,0,0}, cXN_ = {0,0,0,0}, cHN_ = {0,0,0,0};
        cR_  = mfma16(hA0a_, xBR[0], cR_);   cR_  = mfma16(hA0b_, xBR[1], cR_);
        cZ_  = mfma16(hA0a_, xBZ[0], cZ_);   cZ_  = mfma16(hA0b_, xBZ[1], cZ_);
        cXN_ = mfma16(hA0a_, xBXN[0], cXN_); cXN_ = mfma16(hA0b_, xBXN[1], cXN_);
        cR_  = mfma16(hA1a_, hBR[0], cR_);   cR_  = mfma16(hA1b_, hBR[1], cR_);
        cZ_  = mfma16(hA1a_, hBZ[0], cZ_);   cZ_  = mfma16(hA1b_, hBZ[1], cZ_);
        cHN_ = mfma16(hA1a_, hBHN[0], cHN_); cHN_ = mfma16(hA1b_, hBHN[1], cHN_);
        float rg_, zg_, ng_;
        rg_ = fast_sigmoid(cR_[0] + br1); zg_ = fast_sigmoid(cZ_[0] + bz1);
        ng_ = fast_tanh(cXN_[0] + bxn1 + rg_*(cHN_[0] + bhn1));
        h1r0 = (1.f - zg_)*ng_ + zg_*h1r0;
        rg_ = fast_sigmoid(cR_[1] + br1); zg_ = fast_sigmoid(cZ_[1] + bz1);
        ng_ = fast_tanh(cXN_[1] + bxn1 + rg_*(cHN_[1] + bhn1));
        h1r1 = (1.f - zg_)*ng_ + zg_*h1r1;
        rg_ = fast_sigmoid(cR_[2] + br1); zg_ = fast_sigmoid(cZ_[2] + bz1);
        ng_ = fast_tanh(cXN_[2] + bxn1 + rg_*(cHN_[2] + bhn1));
        h1r2 = (1.f - zg_)*ng_ + zg_*h1r2;
        rg_ = fast_sigmoid(cR_[3] + br1); zg_ = fast_sigmoid(cZ_[3] + bz1);
        ng_ = fast_tanh(cXN_[3] + bxn1 + rg_*(cHN_[3] + bhn1));
        h1r3 = (1.f - zg_)*ng_ + zg_*h1r3;
    }

    // ---- pred head: f32 finals via LDS scratch (weights region dead) ----
    __syncthreads();
    float* s0 = reinterpret_cast<float*>(sm);
    float* s1 = reinterpret_cast<float*>(sm) + 1024;
    #pragma unroll
    for (int j = 0; j < 4; ++j){
        int row = 4*q + j;
        float h0v = (j == 0) ? h0r0 : (j == 1) ? h0r1 : (j == 2) ? h0r2 : h0r3;
        float h1v = (j == 0) ? h1r0 : (j == 1) ? h1r1 : (j == 2) ? h1r2 : h1r3;
        s0[row*64 + 16*w + c] = h0v;
        s1[row*64 + 16*w + c] = h1v;
    }
    __syncthreads();
    {
        const int r = tid >> 4, cg = tid & 15;
        const float* hp0 = s0 + r*64 + 4*cg;
        const float* hp1 = s1 + r*64 + 4*cg;
        const float* wp0 = Wpred + 4*cg;
        const float* wp1 = Wpred + 64 + 4*cg;
        float part = hp0[0]*wp0[0] + hp0[1]*wp0[1] + hp0[2]*wp0[2] + hp0[3]*wp0[3]
                   + hp1[0]*wp1[0] + hp1[1]*wp1[1] + hp1[2]*wp1[2] + hp1[3]*wp1[3];
        part += __shfl_xor(part, 8);
        part += __shfl_xor(part, 4);
        part += __shfl_xor(part, 2);
        part += __shfl_xor(part, 1);
        if (cg == 0) outp[B0 + r] = fast_tanh(part + bpred[0]);
    }
#undef RSTEP
}

// ---------- launcher ----------
extern "C" void kernel_launch(void* const* d_in, const int* in_sizes, int n_in,
                              void* d_out, int out_size, void* d_ws, size_t ws_size,
                              hipStream_t stream) {
    (void)in_sizes; (void)n_in; (void)out_size; (void)ws_size;
    const float* station_nodes    = (const float*)d_in[1];
    const float* station_features = (const float*)d_in[2];
    const int*   station_emb      = (const int*)d_in[3];
    const float* e0 = (const float*)d_in[4];
    const float* e1 = (const float*)d_in[5];
    const float* e2 = (const float*)d_in[6];
    const float* e3 = (const float*)d_in[7];
    const float* e4 = (const float*)d_in[8];
    const float* W_nodes = (const float*)d_in[9];
    const float* b_nodes = (const float*)d_in[10];
    const float* W_attn  = (const float*)d_in[11];
    const float* W_d1 = (const float*)d_in[13];
    const float* b_d1 = (const float*)d_in[14];
    const float* W_d2 = (const float*)d_in[15];
    const float* b_d2 = (const float*)d_in[16];
    const float* Wih0 = (const float*)d_in[17];
    const float* Whh0 = (const float*)d_in[18];
    const float* bih0 = (const float*)d_in[19];
    const float* bhh0 = (const float*)d_in[20];
    const float* Wih1 = (const float*)d_in[21];
    const float* Whh1 = (const float*)d_in[22];
    const float* bih1 = (const float*)d_in[23];
    const float* bhh1 = (const float*)d_in[24];
    const float* W_pred = (const float*)d_in[25];
    const float* b_pred = (const float*)d_in[26];
    float* outp = (float*)d_out;

    char* ws = (char*)d_ws;
    float* attnW = (float*)ws;                 // 512 KiB
    u32*   xg0F  = (u32*)(ws + (1u<<20));      // 128*168*1536 u32 = 132 MB

    hipFuncSetAttribute((const void*)nbst_recf,
                        hipFuncAttributeMaxDynamicSharedMemorySize, 96*1024);

    nbst_attn<<<dim3(512), dim3(256), 0, stream>>>(station_nodes, W_nodes, b_nodes, W_attn, attnW);
    nbst_mlpxg0<<<dim3(768), dim3(256), 0, stream>>>(
        station_features, station_emb, e0, e1, e2, e3, e4,
        W_d1, b_d1, W_d2, b_d2, Wih0, attnW, xg0F);
    nbst_recf<<<dim3(128), dim3(256), RF_TOT*4, stream>>>(
        xg0F, Whh0, bih0, bhh0, Wih1, Whh1, bih1, bhh1,
        W_pred, b_pred, outp);
}